// Round 1
// baseline (2715.368 us; speedup 1.0000x reference)
//
#include <hip/hip_runtime.h>
#include <math.h>

#define N_TOK 4096
#define D_EMB 1024
#define T_SEQ 2048
#define NHEAD 16
#define HDIM  64
#define NEXP  8
#define EDIM  2048
#define EPSV  1e-5f

// ---------------- rmsnorm: one block per row (1024 f32 = 256 float4) ----------------
__global__ __launch_bounds__(256) void rmsnorm_kernel(const float* __restrict__ x,
                                                      float* __restrict__ y) {
    int row = blockIdx.x;
    const float* xr = x + (size_t)row * D_EMB;
    float4 v = ((const float4*)xr)[threadIdx.x];
    float ss = v.x*v.x + v.y*v.y + v.z*v.z + v.w*v.w;
    #pragma unroll
    for (int off = 32; off; off >>= 1) ss += __shfl_xor(ss, off);
    __shared__ float wsum[4];
    if ((threadIdx.x & 63) == 0) wsum[threadIdx.x >> 6] = ss;
    __syncthreads();
    float tot = wsum[0] + wsum[1] + wsum[2] + wsum[3];
    float r = rsqrtf(tot * (1.0f / D_EMB) + EPSV);
    float4 o; o.x = v.x*r; o.y = v.y*r; o.z = v.z*r; o.w = v.w*r;
    ((float4*)(y + (size_t)row * D_EMB))[threadIdx.x] = o;
}

// ---------------- dense GEMM: C[n][m] = A[n][:]K @ B[:][m], 64x64 tile, BK=16 ----------------
// EPI: 0 = plain store, 1 = residual add (C = res + acc)
template<int EPI>
__global__ __launch_bounds__(256) void gemm_dense(const float* __restrict__ A,
                                                  const float* __restrict__ B,
                                                  const float* __restrict__ res,
                                                  float* __restrict__ C,
                                                  int K, int M) {
    __shared__ float As[16][64];
    __shared__ float Bs[16][64];
    const int tx = threadIdx.x & 15, ty = threadIdx.x >> 4;
    const int n0 = blockIdx.y * 64, m0 = blockIdx.x * 64;
    const int ra = threadIdx.x >> 2, ca = (threadIdx.x & 3) * 4;
    const int rb = threadIdx.x >> 4, cb = (threadIdx.x & 15) * 4;
    float acc[4][4] = {};
    for (int k0 = 0; k0 < K; k0 += 16) {
        float4 a4 = *(const float4*)(A + (size_t)(n0 + ra) * K + k0 + ca);
        float4 b4 = *(const float4*)(B + (size_t)(k0 + rb) * M + m0 + cb);
        As[ca + 0][ra] = a4.x; As[ca + 1][ra] = a4.y;
        As[ca + 2][ra] = a4.z; As[ca + 3][ra] = a4.w;
        *(float4*)&Bs[rb][cb] = b4;
        __syncthreads();
        #pragma unroll
        for (int kk = 0; kk < 16; kk++) {
            float4 av = *(float4*)&As[kk][ty * 4];
            float4 bv = *(float4*)&Bs[kk][tx * 4];
            float a_[4] = {av.x, av.y, av.z, av.w};
            float b_[4] = {bv.x, bv.y, bv.z, bv.w};
            #pragma unroll
            for (int i = 0; i < 4; i++)
                #pragma unroll
                for (int j = 0; j < 4; j++) acc[i][j] += a_[i] * b_[j];
        }
        __syncthreads();
    }
    #pragma unroll
    for (int i = 0; i < 4; i++) {
        int row = n0 + ty * 4 + i;
        size_t off = (size_t)row * M + m0 + tx * 4;
        float4 o = {acc[i][0], acc[i][1], acc[i][2], acc[i][3]};
        if (EPI == 1) {
            float4 r4 = *(const float4*)(res + off);
            o.x += r4.x; o.y += r4.y; o.z += r4.z; o.w += r4.w;
        }
        *(float4*)(C + off) = o;
    }
}

// ---------------- grouped (per-expert) GEMM with optional row gather ----------------
// EPI: 0 = plain, 2 = squared-relu
template<int EPI, int GATHER>
__global__ __launch_bounds__(256) void gemm_group(const float* __restrict__ A,
                                                  const float* __restrict__ Ball,
                                                  float* __restrict__ C,
                                                  const int* __restrict__ rowmap,
                                                  const int* __restrict__ counts,
                                                  const int* __restrict__ offs,
                                                  int K, int M) {
    const int e = blockIdx.z;
    const int cnt = counts[e];
    const int by = blockIdx.y;
    if (by * 64 >= cnt) return;
    const int base = offs[e];
    const float* B = Ball + (size_t)e * K * M;
    __shared__ float As[16][64];
    __shared__ float Bs[16][64];
    const int tx = threadIdx.x & 15, ty = threadIdx.x >> 4;
    const int m0 = blockIdx.x * 64;
    const int ra = threadIdx.x >> 2, ca = (threadIdx.x & 3) * 4;
    const int rb = threadIdx.x >> 4, cb = (threadIdx.x & 15) * 4;
    const int lr = by * 64 + ra;
    const bool av = lr < cnt;
    int arow = 0;
    if (av) arow = GATHER ? rowmap[base + lr] : (base + lr);
    float acc[4][4] = {};
    for (int k0 = 0; k0 < K; k0 += 16) {
        float4 a4 = {0.f, 0.f, 0.f, 0.f};
        if (av) a4 = *(const float4*)(A + (size_t)arow * K + k0 + ca);
        float4 b4 = *(const float4*)(B + (size_t)(k0 + rb) * M + m0 + cb);
        As[ca + 0][ra] = a4.x; As[ca + 1][ra] = a4.y;
        As[ca + 2][ra] = a4.z; As[ca + 3][ra] = a4.w;
        *(float4*)&Bs[rb][cb] = b4;
        __syncthreads();
        #pragma unroll
        for (int kk = 0; kk < 16; kk++) {
            float4 avv = *(float4*)&As[kk][ty * 4];
            float4 bvv = *(float4*)&Bs[kk][tx * 4];
            float a_[4] = {avv.x, avv.y, avv.z, avv.w};
            float b_[4] = {bvv.x, bvv.y, bvv.z, bvv.w};
            #pragma unroll
            for (int i = 0; i < 4; i++)
                #pragma unroll
                for (int j = 0; j < 4; j++) acc[i][j] += a_[i] * b_[j];
        }
        __syncthreads();
    }
    #pragma unroll
    for (int i = 0; i < 4; i++) {
        int lr2 = by * 64 + ty * 4 + i;
        if (lr2 >= cnt) continue;
        size_t off = (size_t)(base + lr2) * M + m0 + tx * 4;
        float4 o = {acc[i][0], acc[i][1], acc[i][2], acc[i][3]};
        if (EPI == 2) {
            float rx = fmaxf(o.x, 0.f), ry = fmaxf(o.y, 0.f);
            float rz = fmaxf(o.z, 0.f), rw = fmaxf(o.w, 0.f);
            o.x = rx * rx; o.y = ry * ry; o.z = rz * rz; o.w = rw * rw;
        }
        *(float4*)(C + off) = o;
    }
}

// ---------------- causal flash attention, fp32 ----------------
// block: 256 thr = 64 q-rows x 4 parts (16 dims each); one block per (b, h, qtile)
__global__ __launch_bounds__(256) void attn_kernel(const float* __restrict__ q,
                                                   const float* __restrict__ k,
                                                   const float* __restrict__ v,
                                                   float* __restrict__ o) {
    __shared__ float Ks[64][64];
    __shared__ float Vs[64][64];
    const int bid = blockIdx.x;
    const int qt = bid & 31;
    const int hh = (bid >> 5) & 15;
    const int b  = bid >> 9;
    const int t = threadIdx.x;
    const int r = t >> 2, p = t & 3;
    const size_t qoff = ((size_t)(b * T_SEQ + qt * 64 + r)) * D_EMB + hh * HDIM + p * 16;
    float qreg[16];
    #pragma unroll
    for (int i4 = 0; i4 < 4; i4++) {
        float4 x4 = *(const float4*)(q + qoff + i4 * 4);
        qreg[i4*4+0] = x4.x; qreg[i4*4+1] = x4.y; qreg[i4*4+2] = x4.z; qreg[i4*4+3] = x4.w;
    }
    float m = -1e30f, l = 0.f;
    float oacc[16] = {};
    const float sc = 0.125f;
    for (int kt = 0; kt <= qt; kt++) {
        #pragma unroll
        for (int i = 0; i < 4; i++) {
            int idx = t + 256 * i;
            int j = idx >> 4, c = (idx & 15) * 4;
            size_t g = ((size_t)(b * T_SEQ + kt * 64 + j)) * D_EMB + hh * HDIM + c;
            *(float4*)&Ks[j][c] = *(const float4*)(k + g);
            *(float4*)&Vs[j][c] = *(const float4*)(v + g);
        }
        __syncthreads();
        const bool last = (kt == qt);
        float s[64];
        #pragma unroll
        for (int j = 0; j < 64; j++) {
            float d = 0.f;
            #pragma unroll
            for (int i4 = 0; i4 < 4; i4++) {
                float4 k4 = *(float4*)&Ks[j][p * 16 + i4 * 4];
                d += qreg[i4*4+0]*k4.x + qreg[i4*4+1]*k4.y + qreg[i4*4+2]*k4.z + qreg[i4*4+3]*k4.w;
            }
            d += __shfl_xor(d, 1);
            d += __shfl_xor(d, 2);
            s[j] = (last && j > r) ? -1e30f : d * sc;
        }
        float mt = m;
        #pragma unroll
        for (int j = 0; j < 64; j++) mt = fmaxf(mt, s[j]);
        float scale = __expf(m - mt);
        m = mt;
        l *= scale;
        #pragma unroll
        for (int i = 0; i < 16; i++) oacc[i] *= scale;
        #pragma unroll
        for (int j = 0; j < 64; j++) {
            float pj = __expf(s[j] - m);
            l += pj;
            #pragma unroll
            for (int i4 = 0; i4 < 4; i4++) {
                float4 v4 = *(float4*)&Vs[j][p * 16 + i4 * 4];
                oacc[i4*4+0] += pj * v4.x; oacc[i4*4+1] += pj * v4.y;
                oacc[i4*4+2] += pj * v4.z; oacc[i4*4+3] += pj * v4.w;
            }
        }
        __syncthreads();
    }
    const float inv = 1.f / l;
    #pragma unroll
    for (int i4 = 0; i4 < 4; i4++) {
        float4 o4 = {oacc[i4*4+0]*inv, oacc[i4*4+1]*inv, oacc[i4*4+2]*inv, oacc[i4*4+3]*inv};
        *(float4*)(o + qoff + i4 * 4) = o4;
    }
}

// ---------------- MoE routing ----------------
__global__ void zero8(int* c) { if (threadIdx.x < NEXP) c[threadIdx.x] = 0; }

__global__ __launch_bounds__(256) void router_kernel(const float* __restrict__ h,
                                                     const float* __restrict__ rw,
                                                     int* __restrict__ idx,
                                                     float* __restrict__ wts,
                                                     int* __restrict__ pos,
                                                     int* __restrict__ counts) {
    const int tok = blockIdx.x * 4 + (threadIdx.x >> 6);
    const int lane = threadIdx.x & 63;
    const float* xr = h + (size_t)tok * D_EMB;
    float acc[NEXP];
    #pragma unroll
    for (int e = 0; e < NEXP; e++) acc[e] = 0.f;
    for (int kk = lane; kk < D_EMB; kk += 64) {
        float xv = xr[kk];
        #pragma unroll
        for (int e = 0; e < NEXP; e++) acc[e] += xv * rw[kk * NEXP + e];
    }
    #pragma unroll
    for (int e = 0; e < NEXP; e++) {
        #pragma unroll
        for (int off = 32; off; off >>= 1) acc[e] += __shfl_xor(acc[e], off);
    }
    if (lane == 0) {
        int b0 = 0; float v0 = acc[0];
        #pragma unroll
        for (int e = 1; e < NEXP; e++) if (acc[e] > v0) { v0 = acc[e]; b0 = e; }
        int b1 = -1; float v1 = -1e30f;
        #pragma unroll
        for (int e = 0; e < NEXP; e++) if (e != b0 && acc[e] > v1) { v1 = acc[e]; b1 = e; }
        float w0 = 1.f / (1.f + __expf(v1 - v0));
        idx[tok * 2 + 0] = b0; idx[tok * 2 + 1] = b1;
        wts[tok * 2 + 0] = w0; wts[tok * 2 + 1] = 1.f - w0;
        pos[tok * 2 + 0] = atomicAdd(&counts[b0], 1);
        pos[tok * 2 + 1] = atomicAdd(&counts[b1], 1);
    }
}

__global__ void offsets_kernel(const int* __restrict__ counts, int* __restrict__ offs) {
    if (threadIdx.x == 0) {
        int s = 0;
        for (int e = 0; e < NEXP; e++) { offs[e] = s; s += counts[e]; }
    }
}

__global__ __launch_bounds__(256) void buildmap_kernel(const int* __restrict__ idx,
                                                       const int* __restrict__ pos,
                                                       const int* __restrict__ offs,
                                                       int* __restrict__ rowmap,
                                                       int* __restrict__ rowpos) {
    const int n = blockIdx.x * 256 + threadIdx.x;
    #pragma unroll
    for (int s = 0; s < 2; s++) {
        int e = idx[n * 2 + s];
        int r = offs[e] + pos[n * 2 + s];
        rowmap[r] = n;
        rowpos[n * 2 + s] = r;
    }
}

__global__ __launch_bounds__(256) void combine_kernel(const float* __restrict__ oe,
                                                      const int* __restrict__ rowpos,
                                                      const float* __restrict__ wts,
                                                      float* __restrict__ out) {
    const int n = blockIdx.x;
    const int r0 = rowpos[n * 2 + 0], r1 = rowpos[n * 2 + 1];
    const float w0 = wts[n * 2 + 0], w1 = wts[n * 2 + 1];
    const int c = threadIdx.x * 4;
    float4 a = *(const float4*)(oe + (size_t)r0 * D_EMB + c);
    float4 b = *(const float4*)(oe + (size_t)r1 * D_EMB + c);
    float4 o = *(float4*)(out + (size_t)n * D_EMB + c);
    o.x += w0 * a.x + w1 * b.x;
    o.y += w0 * a.y + w1 * b.y;
    o.z += w0 * a.z + w1 * b.z;
    o.w += w0 * a.w + w1 * b.w;
    *(float4*)(out + (size_t)n * D_EMB + c) = o;
}

extern "C" void kernel_launch(void* const* d_in, const int* in_sizes, int n_in,
                              void* d_out, int out_size, void* d_ws, size_t ws_size,
                              hipStream_t stream) {
    (void)in_sizes; (void)n_in; (void)out_size; (void)ws_size;
    const float* x   = (const float*)d_in[0];
    const float* wq  = (const float*)d_in[1];
    const float* wk  = (const float*)d_in[2];
    const float* wv  = (const float*)d_in[3];
    const float* wo  = (const float*)d_in[4];
    const float* rw  = (const float*)d_in[5];
    const float* fc1 = (const float*)d_in[6];
    const float* fc2 = (const float*)d_in[7];
    float* out = (float*)d_out;
    char* ws = (char*)d_ws;
    const size_t MB = 1024 * 1024;

    float* h   = (float*)(ws + 0 * MB);    // 16 MB (rmsnorm out; reused for h2)
    float* q   = (float*)(ws + 16 * MB);   // 16 MB
    float* kk  = (float*)(ws + 32 * MB);   // 16 MB
    float* vv  = (float*)(ws + 48 * MB);   // 16 MB
    float* ao  = (float*)(ws + 64 * MB);   // 16 MB
    float* h1b = (float*)(ws + 16 * MB);   // 64 MB, reuses q/k/v/ao (dead after WO-GEMM)
    float* oeb = (float*)(ws + 80 * MB);   // 32 MB
    char* meta = ws + 112 * MB;
    int*   idx    = (int*)(meta + 0 * 65536);
    int*   pos    = (int*)(meta + 1 * 65536);
    int*   rowmap = (int*)(meta + 2 * 65536);
    int*   rowpos = (int*)(meta + 3 * 65536);
    float* wts    = (float*)(meta + 4 * 65536);
    int*   counts = (int*)(meta + 5 * 65536);
    int*   offs   = (int*)(meta + 5 * 65536 + 256);

    dim3 blk(256);
    dim3 gP(D_EMB / 64, N_TOK / 64);          // dense proj GEMMs: 16 x 64

    rmsnorm_kernel<<<N_TOK, blk, 0, stream>>>(x, h);
    gemm_dense<0><<<gP, blk, 0, stream>>>(h, wq, nullptr, q,  D_EMB, D_EMB);
    gemm_dense<0><<<gP, blk, 0, stream>>>(h, wk, nullptr, kk, D_EMB, D_EMB);
    gemm_dense<0><<<gP, blk, 0, stream>>>(h, wv, nullptr, vv, D_EMB, D_EMB);
    attn_kernel<<<2 * NHEAD * (T_SEQ / 64), blk, 0, stream>>>(q, kk, vv, ao);
    gemm_dense<1><<<gP, blk, 0, stream>>>(ao, wo, x, out, D_EMB, D_EMB);

    rmsnorm_kernel<<<N_TOK, blk, 0, stream>>>(out, h);
    zero8<<<1, 64, 0, stream>>>(counts);
    router_kernel<<<N_TOK / 4, blk, 0, stream>>>(h, rw, idx, wts, pos, counts);
    offsets_kernel<<<1, 64, 0, stream>>>(counts, offs);
    buildmap_kernel<<<N_TOK / 256, blk, 0, stream>>>(idx, pos, offs, rowmap, rowpos);
    gemm_group<2, 1><<<dim3(EDIM / 64, 128, NEXP), blk, 0, stream>>>(
        h, fc1, h1b, rowmap, counts, offs, D_EMB, EDIM);
    gemm_group<0, 0><<<dim3(D_EMB / 64, 128, NEXP), blk, 0, stream>>>(
        h1b, fc2, oeb, rowmap, counts, offs, EDIM, D_EMB);
    combine_kernel<<<N_TOK, blk, 0, stream>>>(oeb, rowpos, wts, out);
}

// Round 3
// 1532.093 us; speedup vs baseline: 1.7723x; 1.7723x over previous
//
#include <hip/hip_runtime.h>
#include <math.h>

#define NTOK 4096
#define DEMB 1024
#define TSEQ 2048
#define QKVS 3072
#define EDIM 2048
#define NEXP 8

typedef unsigned short u16;
typedef unsigned int u32;
typedef __bf16 bf16_t;
typedef __bf16 bf16x8 __attribute__((ext_vector_type(8)));
typedef __bf16 bf16x4 __attribute__((ext_vector_type(4)));
typedef float f32x4 __attribute__((ext_vector_type(4)));

__device__ __forceinline__ f32x4 mfma16(bf16x8 a, bf16x8 b, f32x4 c) {
    return __builtin_amdgcn_mfma_f32_16x16x32_bf16(a, b, c, 0, 0, 0);
}
__device__ __forceinline__ void gll16(const void* g, void* l) {
    __builtin_amdgcn_global_load_lds((const __attribute__((address_space(1))) u32*)g,
                                     (__attribute__((address_space(3))) u32*)l, 16, 0, 0);
}

// ---------------- rmsnorm fp32 -> split bf16 (hi, lo) ----------------
__global__ __launch_bounds__(256) void rmsnorm_split_k(const float* __restrict__ x,
                                                       bf16_t* __restrict__ hi,
                                                       bf16_t* __restrict__ lo) {
    const int row = blockIdx.x;
    const float4 v = ((const float4*)(x + (size_t)row * DEMB))[threadIdx.x];
    float ss = v.x*v.x + v.y*v.y + v.z*v.z + v.w*v.w;
    #pragma unroll
    for (int off = 32; off; off >>= 1) ss += __shfl_xor(ss, off);
    __shared__ float wsum[4];
    if ((threadIdx.x & 63) == 0) wsum[threadIdx.x >> 6] = ss;
    __syncthreads();
    const float r = rsqrtf((wsum[0]+wsum[1]+wsum[2]+wsum[3]) * (1.0f/DEMB) + 1e-5f);
    const float f[4] = {v.x*r, v.y*r, v.z*r, v.w*r};
    bf16x4 hv, lv;
    #pragma unroll
    for (int j = 0; j < 4; j++) {
        const __bf16 hb = (__bf16)f[j];
        hv[j] = hb;
        lv[j] = (__bf16)(f[j] - (float)hb);
    }
    ((bf16x4*)(hi + (size_t)row*DEMB))[threadIdx.x] = hv;
    ((bf16x4*)(lo + (size_t)row*DEMB))[threadIdx.x] = lv;
}

// ---------------- rmsnorm fp32 -> plain bf16 ----------------
__global__ __launch_bounds__(256) void rmsnorm_bf_k(const float* __restrict__ x,
                                                    bf16_t* __restrict__ y) {
    const int row = blockIdx.x;
    const float4 v = ((const float4*)(x + (size_t)row * DEMB))[threadIdx.x];
    float ss = v.x*v.x + v.y*v.y + v.z*v.z + v.w*v.w;
    #pragma unroll
    for (int off = 32; off; off >>= 1) ss += __shfl_xor(ss, off);
    __shared__ float wsum[4];
    if ((threadIdx.x & 63) == 0) wsum[threadIdx.x >> 6] = ss;
    __syncthreads();
    const float r = rsqrtf((wsum[0]+wsum[1]+wsum[2]+wsum[3]) * (1.0f/DEMB) + 1e-5f);
    bf16x4 o;
    o[0] = (__bf16)(v.x*r); o[1] = (__bf16)(v.y*r);
    o[2] = (__bf16)(v.z*r); o[3] = (__bf16)(v.w*r);
    ((bf16x4*)(y + (size_t)row*DEMB))[threadIdx.x] = o;
}

// ---------------- weight transpose fp32 [K][M] -> split bf16 [M][K] ----------------
__global__ __launch_bounds__(256) void transp_split_k(const float* __restrict__ w,
                                                      bf16_t* __restrict__ wth,
                                                      bf16_t* __restrict__ wtl,
                                                      int K, int M) {
    __shared__ float t[32][33];
    const int m0 = blockIdx.x*32, k0 = blockIdx.y*32;
    const int tx = threadIdx.x & 31, ty = threadIdx.x >> 5;
    #pragma unroll
    for (int i = 0; i < 32; i += 8) t[ty+i][tx] = w[(size_t)(k0+ty+i)*M + m0+tx];
    __syncthreads();
    #pragma unroll
    for (int i = 0; i < 32; i += 8) {
        const float f = t[tx][ty+i];
        const __bf16 hb = (__bf16)f;
        wth[(size_t)(m0+ty+i)*K + k0+tx] = hb;
        wtl[(size_t)(m0+ty+i)*K + k0+tx] = (__bf16)(f - (float)hb);
    }
}

// ---------------- weight transpose fp32 [K][M] -> plain bf16 [M][K] (per expert) ------
__global__ __launch_bounds__(256) void transp_k(const float* __restrict__ w,
                                                bf16_t* __restrict__ wt,
                                                int K, int M) {
    __shared__ float t[32][33];
    const size_t eo = (size_t)blockIdx.z * K * M;
    w += eo; wt += eo;
    const int m0 = blockIdx.x*32, k0 = blockIdx.y*32;
    const int tx = threadIdx.x & 31, ty = threadIdx.x >> 5;
    #pragma unroll
    for (int i = 0; i < 32; i += 8) t[ty+i][tx] = w[(size_t)(k0+ty+i)*M + m0+tx];
    __syncthreads();
    #pragma unroll
    for (int i = 0; i < 32; i += 8) wt[(size_t)(m0+ty+i)*K + k0+tx] = (__bf16)t[tx][ty+i];
}

// ---------------- split-bf16 GEMM: C = (Ah+Al)(Bh+Bl)^T, 3 MFMA products, fp32 out ----
// EPI 0: plain fp32 store; EPI 1: fp32 store = res + acc
template<int EPI>
__global__ __launch_bounds__(256) void gemm_split(const bf16_t* __restrict__ Ah,
                                                  const bf16_t* __restrict__ Al,
                                                  const bf16_t* __restrict__ Bh,
                                                  const bf16_t* __restrict__ Bl,
                                                  const float* __restrict__ res,
                                                  float* __restrict__ C,
                                                  int N, int K) {
    __shared__ u16 AsH[128*32];
    __shared__ u16 AsL[128*32];
    __shared__ u16 BsH[128*32];
    __shared__ u16 BsL[128*32];
    const int tid = threadIdx.x;
    const int lane = tid & 63, w = tid >> 6;
    const int lr = lane & 15, lg = lane >> 4;
    const int wm = w >> 1, wn = w & 1;
    const int m0 = blockIdx.y * 128, n0 = blockIdx.x * 128;
    const int rs = tid >> 2, ks = (tid & 3) * 8;
    const size_t arow0 = (size_t)(m0 + rs) * K + ks;
    const size_t arow1 = (size_t)(m0 + 64 + rs) * K + ks;
    const size_t brow0 = (size_t)(n0 + rs) * K + ks;
    const size_t brow1 = (size_t)(n0 + 64 + rs) * K + ks;
    char* lah = (char*)AsH + tid*16;
    char* lal = (char*)AsL + tid*16;
    char* lbh = (char*)BsH + tid*16;
    char* lbl = (char*)BsL + tid*16;
    f32x4 acc[4][4] = {};
    for (int k0 = 0; k0 < K; k0 += 32) {
        __syncthreads();
        gll16(Ah + arow0 + k0, lah); gll16(Ah + arow1 + k0, lah + 4096);
        gll16(Al + arow0 + k0, lal); gll16(Al + arow1 + k0, lal + 4096);
        gll16(Bh + brow0 + k0, lbh); gll16(Bh + brow1 + k0, lbh + 4096);
        gll16(Bl + brow0 + k0, lbl); gll16(Bl + brow1 + k0, lbl + 4096);
        __syncthreads();
        bf16x8 ah[4], al[4], bh[4], bl[4];
        #pragma unroll
        for (int i = 0; i < 4; i++) {
            const int ao = (wm*64 + i*16 + lr)*32 + lg*8;
            const int bo = (wn*64 + i*16 + lr)*32 + lg*8;
            ah[i] = *(const bf16x8*)&AsH[ao];
            al[i] = *(const bf16x8*)&AsL[ao];
            bh[i] = *(const bf16x8*)&BsH[bo];
            bl[i] = *(const bf16x8*)&BsL[bo];
        }
        #pragma unroll
        for (int i = 0; i < 4; i++)
            #pragma unroll
            for (int j = 0; j < 4; j++) {
                acc[i][j] = mfma16(ah[i], bh[j], acc[i][j]);
                acc[i][j] = mfma16(ah[i], bl[j], acc[i][j]);
                acc[i][j] = mfma16(al[i], bh[j], acc[i][j]);
            }
    }
    #pragma unroll
    for (int i = 0; i < 4; i++) {
        #pragma unroll
        for (int j = 0; j < 4; j++) {
            const int row = m0 + wm*64 + i*16 + lg*4;
            const int col = n0 + wn*64 + j*16 + lr;
            const f32x4 v = acc[i][j];
            #pragma unroll
            for (int r = 0; r < 4; r++) {
                const size_t o = (size_t)(row + r) * N + col;
                C[o] = (EPI == 1) ? (res[o] + v[r]) : v[r];
            }
        }
    }
}

// ---------------- grouped per-expert bf16 GEMM (EPI 2: relu^2; EPI 3: plain) ----------
template<int EPI, int GATHER>
__global__ __launch_bounds__(256) void gemm_moe(const bf16_t* __restrict__ A,
                                                const bf16_t* __restrict__ Ball,
                                                bf16_t* __restrict__ C,
                                                const int* __restrict__ rowmap,
                                                const int* __restrict__ counts,
                                                const int* __restrict__ offs,
                                                int N, int K) {
    const int e = blockIdx.z;
    const int cnt = counts[e];
    if ((int)blockIdx.y * 128 >= cnt) return;
    const int base = offs[e];
    const bf16_t* Bt = Ball + (size_t)e * N * K;
    __shared__ u16 As[128*32];
    __shared__ u16 Bs[128*32];
    const int tid = threadIdx.x;
    const int lane = tid & 63, w = tid >> 6;
    const int lr = lane & 15, lg = lane >> 4;
    const int wm = w >> 1, wn = w & 1;
    const int m0 = blockIdx.y * 128, n0 = blockIdx.x * 128;
    const int rs = tid >> 2, ks = (tid & 3) * 8;
    const int l0 = min(m0 + rs, cnt - 1), l1 = min(m0 + 64 + rs, cnt - 1);
    const size_t r0 = GATHER ? (size_t)rowmap[base + l0] : (size_t)(base + l0);
    const size_t r1 = GATHER ? (size_t)rowmap[base + l1] : (size_t)(base + l1);
    const bf16_t* ga0 = A  + r0 * K + ks;
    const bf16_t* ga1 = A  + r1 * K + ks;
    const bf16_t* gb0 = Bt + (size_t)(n0 + rs)      * K + ks;
    const bf16_t* gb1 = Bt + (size_t)(n0 + 64 + rs) * K + ks;
    char* la0 = (char*)As + tid*16; char* la1 = la0 + 4096;
    char* lb0 = (char*)Bs + tid*16; char* lb1 = lb0 + 4096;
    f32x4 acc[4][4] = {};
    for (int k0 = 0; k0 < K; k0 += 32) {
        __syncthreads();
        gll16(ga0 + k0, la0); gll16(ga1 + k0, la1);
        gll16(gb0 + k0, lb0); gll16(gb1 + k0, lb1);
        __syncthreads();
        bf16x8 af[4], bfr[4];
        #pragma unroll
        for (int i = 0; i < 4; i++) {
            af[i]  = *(const bf16x8*)&As[(wm*64 + i*16 + lr)*32 + lg*8];
            bfr[i] = *(const bf16x8*)&Bs[(wn*64 + i*16 + lr)*32 + lg*8];
        }
        #pragma unroll
        for (int i = 0; i < 4; i++)
            #pragma unroll
            for (int j = 0; j < 4; j++)
                acc[i][j] = mfma16(af[i], bfr[j], acc[i][j]);
    }
    #pragma unroll
    for (int i = 0; i < 4; i++) {
        #pragma unroll
        for (int j = 0; j < 4; j++) {
            const int rowl = m0 + wm*64 + i*16 + lg*4;
            const int col  = n0 + wn*64 + j*16 + lr;
            const f32x4 v = acc[i][j];
            #pragma unroll
            for (int r = 0; r < 4; r++) {
                if (rowl + r < cnt) {
                    float xv = v[r];
                    if (EPI == 2) { xv = fmaxf(xv, 0.f); xv = xv * xv; }
                    C[(size_t)(base + rowl + r) * N + col] = (__bf16)xv;
                }
            }
        }
    }
}

// ---------------- causal flash attention, fp32 (proven round-1 core) ----------------
// qkv fp32 [4096][3072] (q|k|v); output split bf16 (hi,lo) [4096][1024]
__global__ __launch_bounds__(256) void attn_kernel(const float* __restrict__ qkv,
                                                   bf16_t* __restrict__ aoh,
                                                   bf16_t* __restrict__ aol) {
    __shared__ float Ks[64][64];
    __shared__ float Vs[64][64];
    const int bid = blockIdx.x;
    const int qt = bid & 31;
    const int hh = (bid >> 5) & 15;
    const int b  = bid >> 9;
    const int t = threadIdx.x;
    const int r = t >> 2, p = t & 3;
    const size_t qoff = ((size_t)(b*TSEQ + qt*64 + r)) * QKVS + hh*64 + p*16;
    const float* kq = qkv + DEMB;
    const float* vq = qkv + 2*DEMB;
    float qreg[16];
    #pragma unroll
    for (int i4 = 0; i4 < 4; i4++) {
        const float4 x4 = *(const float4*)(qkv + qoff + i4*4);
        qreg[i4*4+0] = x4.x; qreg[i4*4+1] = x4.y; qreg[i4*4+2] = x4.z; qreg[i4*4+3] = x4.w;
    }
    float m = -1e30f, l = 0.f;
    float oacc[16] = {};
    const float sc = 0.125f;
    for (int kt = 0; kt <= qt; kt++) {
        #pragma unroll
        for (int i = 0; i < 4; i++) {
            const int idx = t + 256*i;
            const int j = idx >> 4, c = (idx & 15) * 4;
            const size_t g = ((size_t)(b*TSEQ + kt*64 + j)) * QKVS + hh*64 + c;
            *(float4*)&Ks[j][c] = *(const float4*)(kq + g);
            *(float4*)&Vs[j][c] = *(const float4*)(vq + g);
        }
        __syncthreads();
        const bool last = (kt == qt);
        float s[64];
        #pragma unroll
        for (int j = 0; j < 64; j++) {
            float d = 0.f;
            #pragma unroll
            for (int i4 = 0; i4 < 4; i4++) {
                const float4 k4 = *(float4*)&Ks[j][p*16 + i4*4];
                d += qreg[i4*4+0]*k4.x + qreg[i4*4+1]*k4.y + qreg[i4*4+2]*k4.z + qreg[i4*4+3]*k4.w;
            }
            d += __shfl_xor(d, 1);
            d += __shfl_xor(d, 2);
            s[j] = (last && j > r) ? -1e30f : d * sc;
        }
        float mt = m;
        #pragma unroll
        for (int j = 0; j < 64; j++) mt = fmaxf(mt, s[j]);
        const float scale = __expf(m - mt);
        m = mt;
        l *= scale;
        #pragma unroll
        for (int i = 0; i < 16; i++) oacc[i] *= scale;
        #pragma unroll
        for (int j = 0; j < 64; j++) {
            const float pj = __expf(s[j] - m);
            l += pj;
            #pragma unroll
            for (int i4 = 0; i4 < 4; i4++) {
                const float4 v4 = *(float4*)&Vs[j][p*16 + i4*4];
                oacc[i4*4+0] += pj*v4.x; oacc[i4*4+1] += pj*v4.y;
                oacc[i4*4+2] += pj*v4.z; oacc[i4*4+3] += pj*v4.w;
            }
        }
        __syncthreads();
    }
    const float inv = 1.f / l;
    const size_t oo = ((size_t)(b*TSEQ + qt*64 + r)) * DEMB + hh*64 + p*16;
    #pragma unroll
    for (int i4 = 0; i4 < 4; i4++) {
        bf16x4 hv, lv;
        #pragma unroll
        for (int j = 0; j < 4; j++) {
            const float f = oacc[i4*4+j] * inv;
            const __bf16 hb = (__bf16)f;
            hv[j] = hb;
            lv[j] = (__bf16)(f - (float)hb);
        }
        *(bf16x4*)(aoh + oo + i4*4) = hv;
        *(bf16x4*)(aol + oo + i4*4) = lv;
    }
}

// ---------------- MoE routing (fp32, rmsnorm folded in) ----------------
__global__ void zero8(int* c) { if (threadIdx.x < NEXP) c[threadIdx.x] = 0; }

__global__ __launch_bounds__(256) void router_k(const float* __restrict__ xout,
                                                const float* __restrict__ rw,
                                                int* __restrict__ idx,
                                                float* __restrict__ wts,
                                                int* __restrict__ pos,
                                                int* __restrict__ counts) {
    const int tok = blockIdx.x * 4 + (threadIdx.x >> 6);
    const int lane = threadIdx.x & 63;
    const float* xr = xout + (size_t)tok * DEMB;
    float ss = 0.f;
    float acc[NEXP];
    #pragma unroll
    for (int e = 0; e < NEXP; e++) acc[e] = 0.f;
    for (int kk = lane; kk < DEMB; kk += 64) {
        const float xv = xr[kk];
        ss += xv * xv;
        #pragma unroll
        for (int e = 0; e < NEXP; e++) acc[e] += xv * rw[kk*NEXP + e];
    }
    #pragma unroll
    for (int off = 32; off; off >>= 1) ss += __shfl_xor(ss, off);
    #pragma unroll
    for (int e = 0; e < NEXP; e++) {
        #pragma unroll
        for (int off = 32; off; off >>= 1) acc[e] += __shfl_xor(acc[e], off);
    }
    if (lane == 0) {
        const float r = rsqrtf(ss * (1.0f/DEMB) + 1e-5f);
        float v[NEXP];
        #pragma unroll
        for (int e = 0; e < NEXP; e++) v[e] = acc[e] * r;
        int b0 = 0; float v0 = v[0];
        #pragma unroll
        for (int e = 1; e < NEXP; e++) if (v[e] > v0) { v0 = v[e]; b0 = e; }
        int b1 = -1; float v1 = -1e30f;
        #pragma unroll
        for (int e = 0; e < NEXP; e++) if (e != b0 && v[e] > v1) { v1 = v[e]; b1 = e; }
        const float w0 = 1.f / (1.f + __expf(v1 - v0));
        idx[tok*2+0] = b0; idx[tok*2+1] = b1;
        wts[tok*2+0] = w0; wts[tok*2+1] = 1.f - w0;
        pos[tok*2+0] = atomicAdd(&counts[b0], 1);
        pos[tok*2+1] = atomicAdd(&counts[b1], 1);
    }
}

__global__ void offsets_k(const int* __restrict__ counts, int* __restrict__ offs) {
    if (threadIdx.x == 0) {
        int s = 0;
        for (int e = 0; e < NEXP; e++) { offs[e] = s; s += counts[e]; }
    }
}

__global__ __launch_bounds__(256) void buildmap_k(const int* __restrict__ idx,
                                                  const int* __restrict__ pos,
                                                  const int* __restrict__ offs,
                                                  int* __restrict__ rowmap,
                                                  int* __restrict__ rowpos) {
    const int n = blockIdx.x * 256 + threadIdx.x;
    #pragma unroll
    for (int s = 0; s < 2; s++) {
        const int e = idx[n*2+s];
        const int r = offs[e] + pos[n*2+s];
        rowmap[r] = n;
        rowpos[n*2+s] = r;
    }
}

__global__ __launch_bounds__(256) void combine_k(const bf16_t* __restrict__ oe,
                                                 const int* __restrict__ rowpos,
                                                 const float* __restrict__ wts,
                                                 float* __restrict__ out) {
    const int n = blockIdx.x;
    const int r0 = rowpos[n*2+0], r1 = rowpos[n*2+1];
    const float w0 = wts[n*2+0], w1 = wts[n*2+1];
    const int c = threadIdx.x * 4;
    const bf16x4 a  = *(const bf16x4*)(oe + (size_t)r0*DEMB + c);
    const bf16x4 b4 = *(const bf16x4*)(oe + (size_t)r1*DEMB + c);
    float4* op = (float4*)(out + (size_t)n*DEMB + c);
    float4 o = *op;
    o.x += w0*(float)a[0] + w1*(float)b4[0];
    o.y += w0*(float)a[1] + w1*(float)b4[1];
    o.z += w0*(float)a[2] + w1*(float)b4[2];
    o.w += w0*(float)a[3] + w1*(float)b4[3];
    *op = o;
}

extern "C" void kernel_launch(void* const* d_in, const int* in_sizes, int n_in,
                              void* d_out, int out_size, void* d_ws, size_t ws_size,
                              hipStream_t stream) {
    (void)in_sizes; (void)n_in; (void)out_size; (void)ws_size;
    const float* x   = (const float*)d_in[0];
    const float* wq  = (const float*)d_in[1];
    const float* wk  = (const float*)d_in[2];
    const float* wv  = (const float*)d_in[3];
    const float* wo  = (const float*)d_in[4];
    const float* rw  = (const float*)d_in[5];
    const float* fc1 = (const float*)d_in[6];
    const float* fc2 = (const float*)d_in[7];
    float* out = (float*)d_out;
    char* ws = (char*)d_ws;
    const size_t MB = 1024*1024;

    // region map (MB), phase-overlaid:
    //  0-16 : wqkv_h(6) wqkv_l(6) wo_h(2) wo_l(2)   [prep -> WO]     -> oe(16) [moe2 -> combine]
    // 16-64 : qkv fp32 (48)                          [QKV -> attn]    -> fc1_t(32)@16 [->moe1]
    // 48-80 :                                                          -> fc2_t(32)@48 [post-WO -> moe2]
    // 64-80 : h_hi(8) h_lo(8) [rms1 -> QKV]          -> ao_h(8) ao_l(8) [attn -> WO]
    // 80-88 : h bf16 (rms2 out)  [-> moe1]
    // 88-120: h1 bf16 (32)       [moe1 -> moe2]
    // 120+  : meta
    bf16_t* wqkv_h = (bf16_t*)(ws);
    bf16_t* wqkv_l = (bf16_t*)(ws + 6*MB);
    bf16_t* wo_h   = (bf16_t*)(ws + 12*MB);
    bf16_t* wo_l   = (bf16_t*)(ws + 14*MB);
    float*  qkv    = (float*)(ws + 16*MB);
    bf16_t* fc1_t  = (bf16_t*)(ws + 16*MB);
    bf16_t* fc2_t  = (bf16_t*)(ws + 48*MB);
    bf16_t* h_hi   = (bf16_t*)(ws + 64*MB);
    bf16_t* h_lo   = (bf16_t*)(ws + 72*MB);
    bf16_t* ao_h   = (bf16_t*)(ws + 64*MB);
    bf16_t* ao_l   = (bf16_t*)(ws + 72*MB);
    bf16_t* h      = (bf16_t*)(ws + 80*MB);
    bf16_t* h1     = (bf16_t*)(ws + 88*MB);
    bf16_t* oe     = (bf16_t*)(ws);
    char* meta = ws + 120*MB;
    int*   idx    = (int*)(meta);
    int*   pos    = (int*)(meta + 64*1024);
    int*   rowmap = (int*)(meta + 128*1024);
    int*   rowpos = (int*)(meta + 192*1024);
    float* wts    = (float*)(meta + 256*1024);
    int*   counts = (int*)(meta + 320*1024);
    int*   offs   = (int*)(meta + 320*1024 + 256);

    const dim3 blk(256);

    // ---- attention path (split-bf16 GEMMs + fp32 core) ----
    transp_split_k<<<dim3(32,32), blk, 0, stream>>>(wq, wqkv_h,               wqkv_l,               1024, 1024);
    transp_split_k<<<dim3(32,32), blk, 0, stream>>>(wk, wqkv_h + 1024*1024,   wqkv_l + 1024*1024,   1024, 1024);
    transp_split_k<<<dim3(32,32), blk, 0, stream>>>(wv, wqkv_h + 2*1024*1024, wqkv_l + 2*1024*1024, 1024, 1024);
    transp_split_k<<<dim3(32,32), blk, 0, stream>>>(wo, wo_h,                 wo_l,                 1024, 1024);
    rmsnorm_split_k<<<NTOK, blk, 0, stream>>>(x, h_hi, h_lo);
    gemm_split<0><<<dim3(QKVS/128, NTOK/128), blk, 0, stream>>>(
        h_hi, h_lo, wqkv_h, wqkv_l, nullptr, qkv, QKVS, 1024);
    attn_kernel<<<2*16*(TSEQ/64), blk, 0, stream>>>(qkv, ao_h, ao_l);
    gemm_split<1><<<dim3(DEMB/128, NTOK/128), blk, 0, stream>>>(
        ao_h, ao_l, wo_h, wo_l, x, out, DEMB, 1024);

    // ---- MoE path (fp32 router, bf16 experts) ----
    transp_k<<<dim3(64,32,8), blk, 0, stream>>>(fc1, fc1_t, 1024, 2048);
    transp_k<<<dim3(32,64,8), blk, 0, stream>>>(fc2, fc2_t, 2048, 1024);
    rmsnorm_bf_k<<<NTOK, blk, 0, stream>>>(out, h);
    zero8<<<1, 64, 0, stream>>>(counts);
    router_k<<<NTOK/4, blk, 0, stream>>>(out, rw, idx, wts, pos, counts);
    offsets_k<<<1, 64, 0, stream>>>(counts, offs);
    buildmap_k<<<NTOK/256, blk, 0, stream>>>(idx, pos, offs, rowmap, rowpos);
    gemm_moe<2,1><<<dim3(EDIM/128, 32, NEXP), blk, 0, stream>>>(
        h, fc1_t, h1, rowmap, counts, offs, EDIM, 1024);
    gemm_moe<3,0><<<dim3(DEMB/128, 32, NEXP), blk, 0, stream>>>(
        h1, fc2_t, oe, rowmap, counts, offs, DEMB, EDIM);
    combine_k<<<NTOK, blk, 0, stream>>>(oe, rowpos, wts, out);
}

// Round 4
// 625.833 us; speedup vs baseline: 4.3388x; 2.4481x over previous
//
#include <hip/hip_runtime.h>
#include <math.h>

#define NTOK 4096
#define DEMB 1024
#define TSEQ 2048
#define QKVS 3072
#define EDIM 2048
#define NEXP 8

typedef unsigned short u16;
typedef unsigned int u32;
typedef __bf16 bf16_t;
typedef __bf16 bf16x8 __attribute__((ext_vector_type(8)));
typedef __bf16 bf16x4 __attribute__((ext_vector_type(4)));
typedef float f32x4 __attribute__((ext_vector_type(4)));

__device__ __forceinline__ f32x4 mfma16(bf16x8 a, bf16x8 b, f32x4 c) {
    return __builtin_amdgcn_mfma_f32_16x16x32_bf16(a, b, c, 0, 0, 0);
}
__device__ __forceinline__ void gll16(const void* g, void* l) {
    __builtin_amdgcn_global_load_lds((const __attribute__((address_space(1))) u32*)g,
                                     (__attribute__((address_space(3))) u32*)l, 16, 0, 0);
}
__device__ __forceinline__ u16 f2bf(float x) {
    union { __bf16 h; u16 u; } c; c.h = (__bf16)x; return c.u;
}

// ---------------- rmsnorm fp32 -> split bf16 (hi, lo) ----------------
__global__ __launch_bounds__(256) void rmsnorm_split_k(const float* __restrict__ x,
                                                       bf16_t* __restrict__ hi,
                                                       bf16_t* __restrict__ lo) {
    const int row = blockIdx.x;
    const float4 v = ((const float4*)(x + (size_t)row * DEMB))[threadIdx.x];
    float ss = v.x*v.x + v.y*v.y + v.z*v.z + v.w*v.w;
    #pragma unroll
    for (int off = 32; off; off >>= 1) ss += __shfl_xor(ss, off);
    __shared__ float wsum[4];
    if ((threadIdx.x & 63) == 0) wsum[threadIdx.x >> 6] = ss;
    __syncthreads();
    const float r = rsqrtf((wsum[0]+wsum[1]+wsum[2]+wsum[3]) * (1.0f/DEMB) + 1e-5f);
    const float f[4] = {v.x*r, v.y*r, v.z*r, v.w*r};
    bf16x4 hv, lv;
    #pragma unroll
    for (int j = 0; j < 4; j++) {
        const __bf16 hb = (__bf16)f[j];
        hv[j] = hb;
        lv[j] = (__bf16)(f[j] - (float)hb);
    }
    ((bf16x4*)(hi + (size_t)row*DEMB))[threadIdx.x] = hv;
    ((bf16x4*)(lo + (size_t)row*DEMB))[threadIdx.x] = lv;
}

// ---------------- rmsnorm fp32 -> plain bf16 ----------------
__global__ __launch_bounds__(256) void rmsnorm_bf_k(const float* __restrict__ x,
                                                    bf16_t* __restrict__ y) {
    const int row = blockIdx.x;
    const float4 v = ((const float4*)(x + (size_t)row * DEMB))[threadIdx.x];
    float ss = v.x*v.x + v.y*v.y + v.z*v.z + v.w*v.w;
    #pragma unroll
    for (int off = 32; off; off >>= 1) ss += __shfl_xor(ss, off);
    __shared__ float wsum[4];
    if ((threadIdx.x & 63) == 0) wsum[threadIdx.x >> 6] = ss;
    __syncthreads();
    const float r = rsqrtf((wsum[0]+wsum[1]+wsum[2]+wsum[3]) * (1.0f/DEMB) + 1e-5f);
    bf16x4 o;
    o[0] = (__bf16)(v.x*r); o[1] = (__bf16)(v.y*r);
    o[2] = (__bf16)(v.z*r); o[3] = (__bf16)(v.w*r);
    ((bf16x4*)(y + (size_t)row*DEMB))[threadIdx.x] = o;
}

// ---------------- weight transpose fp32 [K][M] -> split bf16 [M][K] ----------------
__global__ __launch_bounds__(256) void transp_split_k(const float* __restrict__ w,
                                                      bf16_t* __restrict__ wth,
                                                      bf16_t* __restrict__ wtl,
                                                      int K, int M) {
    __shared__ float t[32][33];
    const int m0 = blockIdx.x*32, k0 = blockIdx.y*32;
    const int tx = threadIdx.x & 31, ty = threadIdx.x >> 5;
    #pragma unroll
    for (int i = 0; i < 32; i += 8) t[ty+i][tx] = w[(size_t)(k0+ty+i)*M + m0+tx];
    __syncthreads();
    #pragma unroll
    for (int i = 0; i < 32; i += 8) {
        const float f = t[tx][ty+i];
        const __bf16 hb = (__bf16)f;
        wth[(size_t)(m0+ty+i)*K + k0+tx] = hb;
        wtl[(size_t)(m0+ty+i)*K + k0+tx] = (__bf16)(f - (float)hb);
    }
}

// ---------------- weight transpose fp32 [K][M] -> plain bf16 [M][K] (per expert) ------
__global__ __launch_bounds__(256) void transp_k(const float* __restrict__ w,
                                                bf16_t* __restrict__ wt,
                                                int K, int M) {
    __shared__ float t[32][33];
    const size_t eo = (size_t)blockIdx.z * K * M;
    w += eo; wt += eo;
    const int m0 = blockIdx.x*32, k0 = blockIdx.y*32;
    const int tx = threadIdx.x & 31, ty = threadIdx.x >> 5;
    #pragma unroll
    for (int i = 0; i < 32; i += 8) t[ty+i][tx] = w[(size_t)(k0+ty+i)*M + m0+tx];
    __syncthreads();
    #pragma unroll
    for (int i = 0; i < 32; i += 8) wt[(size_t)(m0+ty+i)*K + k0+tx] = (__bf16)t[tx][ty+i];
}

// ---------------- split-bf16 GEMM: C = (Ah+Al)(Bh+Bl)^T, 3 MFMA products ----
// EPI 1: fp32 store = res + acc; EPI 2: split bf16 store (SCALEQ: cols<1024 * 0.125)
template<int EPI, int SCALEQ>
__global__ __launch_bounds__(256) void gemm_split(const bf16_t* __restrict__ Ah,
                                                  const bf16_t* __restrict__ Al,
                                                  const bf16_t* __restrict__ Bh,
                                                  const bf16_t* __restrict__ Bl,
                                                  const float* __restrict__ res,
                                                  float* __restrict__ C,
                                                  bf16_t* __restrict__ Ch,
                                                  bf16_t* __restrict__ Cl,
                                                  int N, int K) {
    __shared__ u16 AsH[128*32];
    __shared__ u16 AsL[128*32];
    __shared__ u16 BsH[128*32];
    __shared__ u16 BsL[128*32];
    const int tid = threadIdx.x;
    const int lane = tid & 63, w = tid >> 6;
    const int lr = lane & 15, lg = lane >> 4;
    const int wm = w >> 1, wn = w & 1;
    const int m0 = blockIdx.y * 128, n0 = blockIdx.x * 128;
    const int rs = tid >> 2, ks = (tid & 3) * 8;
    const size_t arow0 = (size_t)(m0 + rs) * K + ks;
    const size_t arow1 = (size_t)(m0 + 64 + rs) * K + ks;
    const size_t brow0 = (size_t)(n0 + rs) * K + ks;
    const size_t brow1 = (size_t)(n0 + 64 + rs) * K + ks;
    char* lah = (char*)AsH + tid*16;
    char* lal = (char*)AsL + tid*16;
    char* lbh = (char*)BsH + tid*16;
    char* lbl = (char*)BsL + tid*16;
    f32x4 acc[4][4] = {};
    for (int k0 = 0; k0 < K; k0 += 32) {
        __syncthreads();
        gll16(Ah + arow0 + k0, lah); gll16(Ah + arow1 + k0, lah + 4096);
        gll16(Al + arow0 + k0, lal); gll16(Al + arow1 + k0, lal + 4096);
        gll16(Bh + brow0 + k0, lbh); gll16(Bh + brow1 + k0, lbh + 4096);
        gll16(Bl + brow0 + k0, lbl); gll16(Bl + brow1 + k0, lbl + 4096);
        __syncthreads();
        bf16x8 ah[4], al[4], bh[4], bl[4];
        #pragma unroll
        for (int i = 0; i < 4; i++) {
            const int ao = (wm*64 + i*16 + lr)*32 + lg*8;
            const int bo = (wn*64 + i*16 + lr)*32 + lg*8;
            ah[i] = *(const bf16x8*)&AsH[ao];
            al[i] = *(const bf16x8*)&AsL[ao];
            bh[i] = *(const bf16x8*)&BsH[bo];
            bl[i] = *(const bf16x8*)&BsL[bo];
        }
        #pragma unroll
        for (int i = 0; i < 4; i++)
            #pragma unroll
            for (int j = 0; j < 4; j++) {
                acc[i][j] = mfma16(ah[i], bh[j], acc[i][j]);
                acc[i][j] = mfma16(ah[i], bl[j], acc[i][j]);
                acc[i][j] = mfma16(al[i], bh[j], acc[i][j]);
            }
    }
    #pragma unroll
    for (int i = 0; i < 4; i++) {
        #pragma unroll
        for (int j = 0; j < 4; j++) {
            const int row = m0 + wm*64 + i*16 + lg*4;
            const int col = n0 + wn*64 + j*16 + lr;
            const f32x4 v = acc[i][j];
            if (EPI == 1) {
                #pragma unroll
                for (int r = 0; r < 4; r++) {
                    const size_t o = (size_t)(row + r) * N + col;
                    C[o] = res[o] + v[r];
                }
            } else {
                const float sc = (SCALEQ && col < DEMB) ? 0.125f : 1.0f;
                #pragma unroll
                for (int r = 0; r < 4; r++) {
                    const size_t o = (size_t)(row + r) * N + col;
                    const float f = v[r] * sc;
                    const __bf16 hb = (__bf16)f;
                    Ch[o] = hb;
                    Cl[o] = (__bf16)(f - (float)hb);
                }
            }
        }
    }
}

// ---------------- grouped per-expert bf16 GEMM (EPI 2: relu^2; EPI 3: plain) ----------
template<int EPI, int GATHER>
__global__ __launch_bounds__(256) void gemm_moe(const bf16_t* __restrict__ A,
                                                const bf16_t* __restrict__ Ball,
                                                bf16_t* __restrict__ C,
                                                const int* __restrict__ rowmap,
                                                const int* __restrict__ counts,
                                                const int* __restrict__ offs,
                                                int N, int K) {
    const int e = blockIdx.z;
    const int cnt = counts[e];
    if ((int)blockIdx.y * 128 >= cnt) return;
    const int base = offs[e];
    const bf16_t* Bt = Ball + (size_t)e * N * K;
    __shared__ u16 As[128*32];
    __shared__ u16 Bs[128*32];
    const int tid = threadIdx.x;
    const int lane = tid & 63, w = tid >> 6;
    const int lr = lane & 15, lg = lane >> 4;
    const int wm = w >> 1, wn = w & 1;
    const int m0 = blockIdx.y * 128, n0 = blockIdx.x * 128;
    const int rs = tid >> 2, ks = (tid & 3) * 8;
    const int l0 = min(m0 + rs, cnt - 1), l1 = min(m0 + 64 + rs, cnt - 1);
    const size_t r0 = GATHER ? (size_t)rowmap[base + l0] : (size_t)(base + l0);
    const size_t r1 = GATHER ? (size_t)rowmap[base + l1] : (size_t)(base + l1);
    const bf16_t* ga0 = A  + r0 * K + ks;
    const bf16_t* ga1 = A  + r1 * K + ks;
    const bf16_t* gb0 = Bt + (size_t)(n0 + rs)      * K + ks;
    const bf16_t* gb1 = Bt + (size_t)(n0 + 64 + rs) * K + ks;
    char* la0 = (char*)As + tid*16; char* la1 = la0 + 4096;
    char* lb0 = (char*)Bs + tid*16; char* lb1 = lb0 + 4096;
    f32x4 acc[4][4] = {};
    for (int k0 = 0; k0 < K; k0 += 32) {
        __syncthreads();
        gll16(ga0 + k0, la0); gll16(ga1 + k0, la1);
        gll16(gb0 + k0, lb0); gll16(gb1 + k0, lb1);
        __syncthreads();
        bf16x8 af[4], bfr[4];
        #pragma unroll
        for (int i = 0; i < 4; i++) {
            af[i]  = *(const bf16x8*)&As[(wm*64 + i*16 + lr)*32 + lg*8];
            bfr[i] = *(const bf16x8*)&Bs[(wn*64 + i*16 + lr)*32 + lg*8];
        }
        #pragma unroll
        for (int i = 0; i < 4; i++)
            #pragma unroll
            for (int j = 0; j < 4; j++)
                acc[i][j] = mfma16(af[i], bfr[j], acc[i][j]);
    }
    #pragma unroll
    for (int i = 0; i < 4; i++) {
        #pragma unroll
        for (int j = 0; j < 4; j++) {
            const int rowl = m0 + wm*64 + i*16 + lg*4;
            const int col  = n0 + wn*64 + j*16 + lr;
            const f32x4 v = acc[i][j];
            #pragma unroll
            for (int r = 0; r < 4; r++) {
                if (rowl + r < cnt) {
                    float xv = v[r];
                    if (EPI == 2) { xv = fmaxf(xv, 0.f); xv = xv * xv; }
                    C[(size_t)(base + rowl + r) * N + col] = (__bf16)xv;
                }
            }
        }
    }
}

// ---------------- split-bf16 MFMA flash attention, causal ----------------
// grid (qt=16, h=16, b=2); 256 thr = 4 waves, each owns 32 q rows; KV tile = 64
// qkv split hi/lo [4096][3072], q pre-scaled by 0.125; out = ao split hi/lo
__global__ __launch_bounds__(256) void attn_mfma(const bf16_t* __restrict__ qh,
                                                 const bf16_t* __restrict__ ql,
                                                 bf16_t* __restrict__ aoh,
                                                 bf16_t* __restrict__ aol) {
    __shared__ u16 KsH[64*64];     // [kv][d], chunk-swizzled
    __shared__ u16 KsL[64*64];
    __shared__ u16 VtH[64*72];     // [d][kv], stride 72
    __shared__ u16 VtL[64*72];
    __shared__ u16 P_H[4*32*72];   // per-wave P (hi) / output bounce
    __shared__ u16 P_L[4*32*72];
    const int tid = threadIdx.x, lane = tid & 63, wv = tid >> 6;
    const int lr = lane & 15, lg = lane >> 4;
    const int qt = blockIdx.x, h = blockIdx.y, b = blockIdx.z;
    const int qb = qt * 128;
    const int wq0 = qb + wv * 32;
    u16* plwH = P_H + wv * 32 * 72;
    u16* plwL = P_L + wv * 32 * 72;

    // Q fragments (hi/lo), q pre-scaled in QKV epilogue
    bf16x8 qfh[2][2], qfl[2][2];
    #pragma unroll
    for (int g = 0; g < 2; g++)
        #pragma unroll
        for (int kf = 0; kf < 2; kf++) {
            const size_t qo = (size_t)(b*TSEQ + wq0 + g*16 + lr) * QKVS + h*64 + kf*32 + lg*8;
            qfh[g][kf] = *(const bf16x8*)(qh + qo);
            qfl[g][kf] = *(const bf16x8*)(ql + qo);
        }

    f32x4 of[4][2] = {};                 // O^T frags [dfrag][qfrag]
    float mrun[2] = {-1e30f, -1e30f}, lrun[2] = {0.f, 0.f};
    const int skv = tid >> 3;                      // staging kv row (0..31)
    const int chs = (tid & 7) ^ (skv & 7);         // swizzled 16B chunk for K
    const int sd8 = (tid & 7) * 8;                 // V d-offset
    const int rot = tid & 7;
    const bf16_t* kbh = qh + DEMB;
    const bf16_t* kbl = ql + DEMB;
    const bf16_t* vbh = qh + 2*DEMB;
    const bf16_t* vbl = ql + 2*DEMB;
    const int nkt = qb/64 + 2;

    for (int kt = 0; kt < nkt; kt++) {
        __syncthreads();
        const size_t krow = (size_t)(b*TSEQ + kt*64 + skv) * QKVS + h*64;
        gll16(kbh + krow + chs*8,                   (char*)KsH + tid*16);
        gll16(kbh + krow + (size_t)32*QKVS + chs*8, (char*)KsH + 4096 + tid*16);
        gll16(kbl + krow + chs*8,                   (char*)KsL + tid*16);
        gll16(kbl + krow + (size_t)32*QKVS + chs*8, (char*)KsL + 4096 + tid*16);
        const bf16x8 vh0 = *(const bf16x8*)(vbh + krow + sd8);
        const bf16x8 vh1 = *(const bf16x8*)(vbh + krow + (size_t)32*QKVS + sd8);
        const bf16x8 vl0 = *(const bf16x8*)(vbl + krow + sd8);
        const bf16x8 vl1 = *(const bf16x8*)(vbl + krow + (size_t)32*QKVS + sd8);
        __syncthreads();
        { // V^T writes (rotate j by lane to spread banks)
            const u16* ph0 = (const u16*)&vh0; const u16* ph1 = (const u16*)&vh1;
            const u16* pl0 = (const u16*)&vl0; const u16* pl1 = (const u16*)&vl1;
            #pragma unroll
            for (int j0 = 0; j0 < 8; j0++) {
                const int j = (j0 + rot) & 7;
                VtH[(sd8 + j)*72 + skv]      = ph0[j];
                VtH[(sd8 + j)*72 + skv + 32] = ph1[j];
                VtL[(sd8 + j)*72 + skv]      = pl0[j];
                VtL[(sd8 + j)*72 + skv + 32] = pl1[j];
            }
        }
        const bool active = (kt*64 <= wq0 + 31);
        if (active) {
            // S^T = K . Q  (3 split products)
            f32x4 sf[4][2] = {};
            #pragma unroll
            for (int kf = 0; kf < 2; kf++)
                #pragma unroll
                for (int f = 0; f < 4; f++) {
                    int idx = (f*16 + lr)*64 + kf*32 + lg*8;
                    idx ^= (lr & 7) << 3;    // unswizzle
                    const bf16x8 ah = *(const bf16x8*)&KsH[idx];
                    const bf16x8 al = *(const bf16x8*)&KsL[idx];
                    #pragma unroll
                    for (int g = 0; g < 2; g++) {
                        sf[f][g] = mfma16(ah, qfh[g][kf], sf[f][g]);
                        sf[f][g] = mfma16(ah, qfl[g][kf], sf[f][g]);
                        sf[f][g] = mfma16(al, qfh[g][kf], sf[f][g]);
                    }
                }
            if (kt*64 + 63 > wq0) {   // causal mask
                #pragma unroll
                for (int f = 0; f < 4; f++)
                    #pragma unroll
                    for (int g = 0; g < 2; g++)
                        #pragma unroll
                        for (int r = 0; r < 4; r++) {
                            const int kvg = kt*64 + f*16 + lg*4 + r;
                            const int qg  = wq0 + g*16 + lr;
                            if (kvg > qg) sf[f][g][r] = -1e30f;
                        }
            }
            #pragma unroll
            for (int g = 0; g < 2; g++) {
                float tm = -1e30f;
                #pragma unroll
                for (int f = 0; f < 4; f++)
                    tm = fmaxf(tm, fmaxf(fmaxf(sf[f][g][0], sf[f][g][1]),
                                         fmaxf(sf[f][g][2], sf[f][g][3])));
                tm = fmaxf(tm, __shfl_xor(tm, 16));
                tm = fmaxf(tm, __shfl_xor(tm, 32));
                const float mnew = fmaxf(mrun[g], tm);
                const float fac = __expf(mrun[g] - mnew);
                mrun[g] = mnew;
                float ps = 0.f;
                #pragma unroll
                for (int f = 0; f < 4; f++) {
                    float p[4];
                    #pragma unroll
                    for (int r = 0; r < 4; r++) {
                        p[r] = __expf(sf[f][g][r] - mnew);
                        ps += p[r];
                    }
                    u16 hbits[4], lbits[4];
                    #pragma unroll
                    for (int r = 0; r < 4; r++) {
                        const __bf16 hb = (__bf16)p[r];
                        hbits[r] = f2bf(p[r]);
                        lbits[r] = f2bf(p[r] - (float)hb);
                    }
                    u32* pwh = (u32*)&plwH[(g*16 + lr)*72 + f*16 + lg*4];
                    u32* pwl = (u32*)&plwL[(g*16 + lr)*72 + f*16 + lg*4];
                    pwh[0] = (u32)hbits[0] | ((u32)hbits[1] << 16);
                    pwh[1] = (u32)hbits[2] | ((u32)hbits[3] << 16);
                    pwl[0] = (u32)lbits[0] | ((u32)lbits[1] << 16);
                    pwl[1] = (u32)lbits[2] | ((u32)lbits[3] << 16);
                }
                ps += __shfl_xor(ps, 16);
                ps += __shfl_xor(ps, 32);
                lrun[g] = lrun[g]*fac + ps;
                #pragma unroll
                for (int f2 = 0; f2 < 4; f2++)
                    #pragma unroll
                    for (int r = 0; r < 4; r++) of[f2][g][r] *= fac;
            }
        }
        __syncthreads();   // Vt visible to all waves
        if (active) {
            // O^T += V^T . P^T  (3 split products)
            #pragma unroll
            for (int hf = 0; hf < 2; hf++) {
                bf16x8 pbh[2], pbl[2];
                #pragma unroll
                for (int g = 0; g < 2; g++) {
                    pbh[g] = *(const bf16x8*)&plwH[(g*16 + lr)*72 + hf*32 + lg*8];
                    pbl[g] = *(const bf16x8*)&plwL[(g*16 + lr)*72 + hf*32 + lg*8];
                }
                #pragma unroll
                for (int f2 = 0; f2 < 4; f2++) {
                    const bf16x8 vah = *(const bf16x8*)&VtH[(f2*16 + lr)*72 + hf*32 + lg*8];
                    const bf16x8 val = *(const bf16x8*)&VtL[(f2*16 + lr)*72 + hf*32 + lg*8];
                    #pragma unroll
                    for (int g = 0; g < 2; g++) {
                        of[f2][g] = mfma16(vah, pbh[g], of[f2][g]);
                        of[f2][g] = mfma16(vah, pbl[g], of[f2][g]);
                        of[f2][g] = mfma16(val, pbh[g], of[f2][g]);
                    }
                }
            }
        }
    }
    // epilogue: normalize, split, transpose via LDS, coalesced split store
    const float inv0 = 1.f / lrun[0], inv1 = 1.f / lrun[1];
    #pragma unroll
    for (int f2 = 0; f2 < 4; f2++)
        #pragma unroll
        for (int g = 0; g < 2; g++) {
            const float iv = g ? inv1 : inv0;
            u16 hbits[4], lbits[4];
            #pragma unroll
            for (int r = 0; r < 4; r++) {
                const float f = of[f2][g][r] * iv;
                const __bf16 hb = (__bf16)f;
                hbits[r] = f2bf(f);
                lbits[r] = f2bf(f - (float)hb);
            }
            u32* pwh = (u32*)&plwH[(g*16 + lr)*72 + f2*16 + lg*4];
            u32* pwl = (u32*)&plwL[(g*16 + lr)*72 + f2*16 + lg*4];
            pwh[0] = (u32)hbits[0] | ((u32)hbits[1] << 16);
            pwh[1] = (u32)hbits[2] | ((u32)hbits[3] << 16);
            pwl[0] = (u32)lbits[0] | ((u32)lbits[1] << 16);
            pwl[1] = (u32)lbits[2] | ((u32)lbits[3] << 16);
        }
    asm volatile("s_waitcnt lgkmcnt(0)" ::: "memory");
    #pragma unroll
    for (int pass = 0; pass < 4; pass++) {
        const int qlr = pass*8 + (lane >> 3);
        const int ch = (lane & 7) * 8;
        const bf16x8 oh = *(const bf16x8*)&plwH[qlr*72 + ch];
        const bf16x8 ol = *(const bf16x8*)&plwL[qlr*72 + ch];
        const size_t go = (size_t)(b*TSEQ + wq0 + qlr) * DEMB + h*64 + ch;
        *(bf16x8*)(aoh + go) = oh;
        *(bf16x8*)(aol + go) = ol;
    }
}

// ---------------- MoE routing (fp32, rmsnorm folded in) ----------------
__global__ void zero8(int* c) { if (threadIdx.x < NEXP) c[threadIdx.x] = 0; }

__global__ __launch_bounds__(256) void router_k(const float* __restrict__ xout,
                                                const float* __restrict__ rw,
                                                int* __restrict__ idx,
                                                float* __restrict__ wts,
                                                int* __restrict__ pos,
                                                int* __restrict__ counts) {
    const int tok = blockIdx.x * 4 + (threadIdx.x >> 6);
    const int lane = threadIdx.x & 63;
    const float* xr = xout + (size_t)tok * DEMB;
    float ss = 0.f;
    float acc[NEXP];
    #pragma unroll
    for (int e = 0; e < NEXP; e++) acc[e] = 0.f;
    for (int kk = lane; kk < DEMB; kk += 64) {
        const float xv = xr[kk];
        ss += xv * xv;
        #pragma unroll
        for (int e = 0; e < NEXP; e++) acc[e] += xv * rw[kk*NEXP + e];
    }
    #pragma unroll
    for (int off = 32; off; off >>= 1) ss += __shfl_xor(ss, off);
    #pragma unroll
    for (int e = 0; e < NEXP; e++) {
        #pragma unroll
        for (int off = 32; off; off >>= 1) acc[e] += __shfl_xor(acc[e], off);
    }
    if (lane == 0) {
        const float r = rsqrtf(ss * (1.0f/DEMB) + 1e-5f);
        float v[NEXP];
        #pragma unroll
        for (int e = 0; e < NEXP; e++) v[e] = acc[e] * r;
        int b0 = 0; float v0 = v[0];
        #pragma unroll
        for (int e = 1; e < NEXP; e++) if (v[e] > v0) { v0 = v[e]; b0 = e; }
        int b1 = -1; float v1 = -1e30f;
        #pragma unroll
        for (int e = 0; e < NEXP; e++) if (e != b0 && v[e] > v1) { v1 = v[e]; b1 = e; }
        const float w0 = 1.f / (1.f + __expf(v1 - v0));
        idx[tok*2+0] = b0; idx[tok*2+1] = b1;
        wts[tok*2+0] = w0; wts[tok*2+1] = 1.f - w0;
        pos[tok*2+0] = atomicAdd(&counts[b0], 1);
        pos[tok*2+1] = atomicAdd(&counts[b1], 1);
    }
}

__global__ void offsets_k(const int* __restrict__ counts, int* __restrict__ offs) {
    if (threadIdx.x == 0) {
        int s = 0;
        for (int e = 0; e < NEXP; e++) { offs[e] = s; s += counts[e]; }
    }
}

__global__ __launch_bounds__(256) void buildmap_k(const int* __restrict__ idx,
                                                  const int* __restrict__ pos,
                                                  const int* __restrict__ offs,
                                                  int* __restrict__ rowmap,
                                                  int* __restrict__ rowpos) {
    const int n = blockIdx.x * 256 + threadIdx.x;
    #pragma unroll
    for (int s = 0; s < 2; s++) {
        const int e = idx[n*2+s];
        const int r = offs[e] + pos[n*2+s];
        rowmap[r] = n;
        rowpos[n*2+s] = r;
    }
}

__global__ __launch_bounds__(256) void combine_k(const bf16_t* __restrict__ oe,
                                                 const int* __restrict__ rowpos,
                                                 const float* __restrict__ wts,
                                                 float* __restrict__ out) {
    const int n = blockIdx.x;
    const int r0 = rowpos[n*2+0], r1 = rowpos[n*2+1];
    const float w0 = wts[n*2+0], w1 = wts[n*2+1];
    const int c = threadIdx.x * 4;
    const bf16x4 a  = *(const bf16x4*)(oe + (size_t)r0*DEMB + c);
    const bf16x4 b4 = *(const bf16x4*)(oe + (size_t)r1*DEMB + c);
    float4* op = (float4*)(out + (size_t)n*DEMB + c);
    float4 o = *op;
    o.x += w0*(float)a[0] + w1*(float)b4[0];
    o.y += w0*(float)a[1] + w1*(float)b4[1];
    o.z += w0*(float)a[2] + w1*(float)b4[2];
    o.w += w0*(float)a[3] + w1*(float)b4[3];
    *op = o;
}

extern "C" void kernel_launch(void* const* d_in, const int* in_sizes, int n_in,
                              void* d_out, int out_size, void* d_ws, size_t ws_size,
                              hipStream_t stream) {
    (void)in_sizes; (void)n_in; (void)out_size; (void)ws_size;
    const float* x   = (const float*)d_in[0];
    const float* wq  = (const float*)d_in[1];
    const float* wk  = (const float*)d_in[2];
    const float* wv  = (const float*)d_in[3];
    const float* wo  = (const float*)d_in[4];
    const float* rw  = (const float*)d_in[5];
    const float* fc1 = (const float*)d_in[6];
    const float* fc2 = (const float*)d_in[7];
    float* out = (float*)d_out;
    char* ws = (char*)d_ws;
    const size_t MB = 1024*1024;

    // region map (MB), phase-overlaid:
    //  0-16 : wqkv_h(6) wqkv_l(6) wo_h(2) wo_l(2) [prep->WO]  -> oe(16) [moe2->combine]
    // 16-64 : qkv_h(24)@16 qkv_l(24)@40 [QKV->attn] -> fc1_t(32)@16, fc2_t(32)@48 [post-WO]
    // 64-80 : h_hi(8) h_lo(8) [rms1->QKV]          -> ao_h(8) ao_l(8) [attn->WO]
    // 80-88 : h bf16 (rms2 out)  [->moe1]
    // 88-120: h1 bf16 (32)       [moe1->moe2]
    // 120+  : meta
    bf16_t* wqkv_h = (bf16_t*)(ws);
    bf16_t* wqkv_l = (bf16_t*)(ws + 6*MB);
    bf16_t* wo_h   = (bf16_t*)(ws + 12*MB);
    bf16_t* wo_l   = (bf16_t*)(ws + 14*MB);
    bf16_t* qkv_h  = (bf16_t*)(ws + 16*MB);
    bf16_t* qkv_l  = (bf16_t*)(ws + 40*MB);
    bf16_t* fc1_t  = (bf16_t*)(ws + 16*MB);
    bf16_t* fc2_t  = (bf16_t*)(ws + 48*MB);
    bf16_t* h_hi   = (bf16_t*)(ws + 64*MB);
    bf16_t* h_lo   = (bf16_t*)(ws + 72*MB);
    bf16_t* ao_h   = (bf16_t*)(ws + 64*MB);
    bf16_t* ao_l   = (bf16_t*)(ws + 72*MB);
    bf16_t* h      = (bf16_t*)(ws + 80*MB);
    bf16_t* h1     = (bf16_t*)(ws + 88*MB);
    bf16_t* oe     = (bf16_t*)(ws);
    char* meta = ws + 120*MB;
    int*   idx    = (int*)(meta);
    int*   pos    = (int*)(meta + 64*1024);
    int*   rowmap = (int*)(meta + 128*1024);
    int*   rowpos = (int*)(meta + 192*1024);
    float* wts    = (float*)(meta + 256*1024);
    int*   counts = (int*)(meta + 320*1024);
    int*   offs   = (int*)(meta + 320*1024 + 256);

    const dim3 blk(256);

    // ---- attention path (split-bf16 GEMMs + split-bf16 MFMA flash attention) ----
    transp_split_k<<<dim3(32,32), blk, 0, stream>>>(wq, wqkv_h,               wqkv_l,               1024, 1024);
    transp_split_k<<<dim3(32,32), blk, 0, stream>>>(wk, wqkv_h + 1024*1024,   wqkv_l + 1024*1024,   1024, 1024);
    transp_split_k<<<dim3(32,32), blk, 0, stream>>>(wv, wqkv_h + 2*1024*1024, wqkv_l + 2*1024*1024, 1024, 1024);
    transp_split_k<<<dim3(32,32), blk, 0, stream>>>(wo, wo_h,                 wo_l,                 1024, 1024);
    rmsnorm_split_k<<<NTOK, blk, 0, stream>>>(x, h_hi, h_lo);
    gemm_split<2,1><<<dim3(QKVS/128, NTOK/128), blk, 0, stream>>>(
        h_hi, h_lo, wqkv_h, wqkv_l, nullptr, nullptr, qkv_h, qkv_l, QKVS, 1024);
    attn_mfma<<<dim3(TSEQ/128, 16, 2), blk, 0, stream>>>(qkv_h, qkv_l, ao_h, ao_l);
    gemm_split<1,0><<<dim3(DEMB/128, NTOK/128), blk, 0, stream>>>(
        ao_h, ao_l, wo_h, wo_l, x, out, nullptr, nullptr, DEMB, 1024);

    // ---- MoE path (fp32 router, bf16 experts) ----
    transp_k<<<dim3(64,32,8), blk, 0, stream>>>(fc1, fc1_t, 1024, 2048);
    transp_k<<<dim3(32,64,8), blk, 0, stream>>>(fc2, fc2_t, 2048, 1024);
    rmsnorm_bf_k<<<NTOK, blk, 0, stream>>>(out, h);
    zero8<<<1, 64, 0, stream>>>(counts);
    router_k<<<NTOK/4, blk, 0, stream>>>(out, rw, idx, wts, pos, counts);
    offsets_k<<<1, 64, 0, stream>>>(counts, offs);
    buildmap_k<<<NTOK/256, blk, 0, stream>>>(idx, pos, offs, rowmap, rowpos);
    gemm_moe<2,1><<<dim3(EDIM/128, 32, NEXP), blk, 0, stream>>>(
        h, fc1_t, h1, rowmap, counts, offs, EDIM, 1024);
    gemm_moe<3,0><<<dim3(DEMB/128, 32, NEXP), blk, 0, stream>>>(
        h1, fc2_t, oe, rowmap, counts, offs, DEMB, EDIM);
    combine_k<<<NTOK, blk, 0, stream>>>(oe, rowpos, wts, out);
}

// Round 5
// 547.998 us; speedup vs baseline: 4.9551x; 1.1420x over previous
//
#include <hip/hip_runtime.h>
#include <math.h>

#define NTOK 4096
#define DEMB 1024
#define TSEQ 2048
#define QKVS 3072
#define QKN  2048
#define EDIM 2048
#define NEXP 8

typedef unsigned short u16;
typedef unsigned int u32;
typedef __bf16 bf16_t;
typedef __bf16 bf16x8 __attribute__((ext_vector_type(8)));
typedef __bf16 bf16x4 __attribute__((ext_vector_type(4)));
typedef float f32x4 __attribute__((ext_vector_type(4)));

__device__ __forceinline__ f32x4 mfma16(bf16x8 a, bf16x8 b, f32x4 c) {
    return __builtin_amdgcn_mfma_f32_16x16x32_bf16(a, b, c, 0, 0, 0);
}
__device__ __forceinline__ void gll16(const void* g, void* l) {
    __builtin_amdgcn_global_load_lds((const __attribute__((address_space(1))) u32*)g,
                                     (__attribute__((address_space(3))) u32*)l, 16, 0, 0);
}
__device__ __forceinline__ u16 f2bf(float x) {
    union { __bf16 h; u16 u; } c; c.h = (__bf16)x; return c.u;
}

// ---------------- rmsnorm fp32 -> split bf16 (hi, lo) ----------------
__global__ __launch_bounds__(256) void rmsnorm_split_k(const float* __restrict__ x,
                                                       bf16_t* __restrict__ hi,
                                                       bf16_t* __restrict__ lo) {
    const int row = blockIdx.x;
    const float4 v = ((const float4*)(x + (size_t)row * DEMB))[threadIdx.x];
    float ss = v.x*v.x + v.y*v.y + v.z*v.z + v.w*v.w;
    #pragma unroll
    for (int off = 32; off; off >>= 1) ss += __shfl_xor(ss, off);
    __shared__ float wsum[4];
    if ((threadIdx.x & 63) == 0) wsum[threadIdx.x >> 6] = ss;
    __syncthreads();
    const float r = rsqrtf((wsum[0]+wsum[1]+wsum[2]+wsum[3]) * (1.0f/DEMB) + 1e-5f);
    const float f[4] = {v.x*r, v.y*r, v.z*r, v.w*r};
    bf16x4 hv, lv;
    #pragma unroll
    for (int j = 0; j < 4; j++) {
        const __bf16 hb = (__bf16)f[j];
        hv[j] = hb;
        lv[j] = (__bf16)(f[j] - (float)hb);
    }
    ((bf16x4*)(hi + (size_t)row*DEMB))[threadIdx.x] = hv;
    ((bf16x4*)(lo + (size_t)row*DEMB))[threadIdx.x] = lv;
}

// ---------------- rmsnorm fp32 -> plain bf16 ----------------
__global__ __launch_bounds__(256) void rmsnorm_bf_k(const float* __restrict__ x,
                                                    bf16_t* __restrict__ y) {
    const int row = blockIdx.x;
    const float4 v = ((const float4*)(x + (size_t)row * DEMB))[threadIdx.x];
    float ss = v.x*v.x + v.y*v.y + v.z*v.z + v.w*v.w;
    #pragma unroll
    for (int off = 32; off; off >>= 1) ss += __shfl_xor(ss, off);
    __shared__ float wsum[4];
    if ((threadIdx.x & 63) == 0) wsum[threadIdx.x >> 6] = ss;
    __syncthreads();
    const float r = rsqrtf((wsum[0]+wsum[1]+wsum[2]+wsum[3]) * (1.0f/DEMB) + 1e-5f);
    bf16x4 o;
    o[0] = (__bf16)(v.x*r); o[1] = (__bf16)(v.y*r);
    o[2] = (__bf16)(v.z*r); o[3] = (__bf16)(v.w*r);
    ((bf16x4*)(y + (size_t)row*DEMB))[threadIdx.x] = o;
}

// ---------------- weight transpose fp32 [K][M] -> split bf16 [M][K] ----------------
__global__ __launch_bounds__(256) void transp_split_k(const float* __restrict__ w,
                                                      bf16_t* __restrict__ wth,
                                                      bf16_t* __restrict__ wtl,
                                                      int K, int M) {
    __shared__ float t[32][33];
    const int m0 = blockIdx.x*32, k0 = blockIdx.y*32;
    const int tx = threadIdx.x & 31, ty = threadIdx.x >> 5;
    #pragma unroll
    for (int i = 0; i < 32; i += 8) t[ty+i][tx] = w[(size_t)(k0+ty+i)*M + m0+tx];
    __syncthreads();
    #pragma unroll
    for (int i = 0; i < 32; i += 8) {
        const float f = t[tx][ty+i];
        const __bf16 hb = (__bf16)f;
        wth[(size_t)(m0+ty+i)*K + k0+tx] = hb;
        wtl[(size_t)(m0+ty+i)*K + k0+tx] = (__bf16)(f - (float)hb);
    }
}

// ---------------- weight transpose fp32 [K][M] -> plain bf16 [M][K] (per expert) ------
__global__ __launch_bounds__(256) void transp_k(const float* __restrict__ w,
                                                bf16_t* __restrict__ wt,
                                                int K, int M) {
    __shared__ float t[32][33];
    const size_t eo = (size_t)blockIdx.z * K * M;
    w += eo; wt += eo;
    const int m0 = blockIdx.x*32, k0 = blockIdx.y*32;
    const int tx = threadIdx.x & 31, ty = threadIdx.x >> 5;
    #pragma unroll
    for (int i = 0; i < 32; i += 8) t[ty+i][tx] = w[(size_t)(k0+ty+i)*M + m0+tx];
    __syncthreads();
    #pragma unroll
    for (int i = 0; i < 32; i += 8) wt[(size_t)(m0+ty+i)*K + k0+tx] = (__bf16)t[tx][ty+i];
}

// ---------------- split-bf16 GEMM: C = (Ah+Al)(Bh+Bl)^T, 3 MFMA products ----
// EPI 1: fp32 store = res + acc
// EPI 3: QKV epilogue -> Q (x0.125) and K split into qk [tok][2048]; V split into V^T [bh*64+d][t]
template<int EPI>
__global__ __launch_bounds__(256) void gemm_split(const bf16_t* __restrict__ Ah,
                                                  const bf16_t* __restrict__ Al,
                                                  const bf16_t* __restrict__ Bh,
                                                  const bf16_t* __restrict__ Bl,
                                                  const float* __restrict__ res,
                                                  float* __restrict__ C,
                                                  bf16_t* __restrict__ qkh,
                                                  bf16_t* __restrict__ qkl,
                                                  bf16_t* __restrict__ vth,
                                                  bf16_t* __restrict__ vtl,
                                                  int N, int K) {
    __shared__ u16 AsH[128*32];
    __shared__ u16 AsL[128*32];
    __shared__ u16 BsH[128*32];
    __shared__ u16 BsL[128*32];
    const int tid = threadIdx.x;
    const int lane = tid & 63, w = tid >> 6;
    const int lr = lane & 15, lg = lane >> 4;
    const int wm = w >> 1, wn = w & 1;
    const int m0 = blockIdx.y * 128, n0 = blockIdx.x * 128;
    const int rs = tid >> 2, ks = (tid & 3) * 8;
    const size_t arow0 = (size_t)(m0 + rs) * K + ks;
    const size_t arow1 = (size_t)(m0 + 64 + rs) * K + ks;
    const size_t brow0 = (size_t)(n0 + rs) * K + ks;
    const size_t brow1 = (size_t)(n0 + 64 + rs) * K + ks;
    char* lah = (char*)AsH + tid*16;
    char* lal = (char*)AsL + tid*16;
    char* lbh = (char*)BsH + tid*16;
    char* lbl = (char*)BsL + tid*16;
    f32x4 acc[4][4] = {};
    for (int k0 = 0; k0 < K; k0 += 32) {
        __syncthreads();
        gll16(Ah + arow0 + k0, lah); gll16(Ah + arow1 + k0, lah + 4096);
        gll16(Al + arow0 + k0, lal); gll16(Al + arow1 + k0, lal + 4096);
        gll16(Bh + brow0 + k0, lbh); gll16(Bh + brow1 + k0, lbh + 4096);
        gll16(Bl + brow0 + k0, lbl); gll16(Bl + brow1 + k0, lbl + 4096);
        __syncthreads();
        bf16x8 ah[4], al[4], bh[4], bl[4];
        #pragma unroll
        for (int i = 0; i < 4; i++) {
            const int ao = (wm*64 + i*16 + lr)*32 + lg*8;
            const int bo = (wn*64 + i*16 + lr)*32 + lg*8;
            ah[i] = *(const bf16x8*)&AsH[ao];
            al[i] = *(const bf16x8*)&AsL[ao];
            bh[i] = *(const bf16x8*)&BsH[bo];
            bl[i] = *(const bf16x8*)&BsL[bo];
        }
        #pragma unroll
        for (int i = 0; i < 4; i++)
            #pragma unroll
            for (int j = 0; j < 4; j++) {
                acc[i][j] = mfma16(ah[i], bh[j], acc[i][j]);
                acc[i][j] = mfma16(ah[i], bl[j], acc[i][j]);
                acc[i][j] = mfma16(al[i], bh[j], acc[i][j]);
            }
    }
    #pragma unroll
    for (int i = 0; i < 4; i++) {
        #pragma unroll
        for (int j = 0; j < 4; j++) {
            const int row = m0 + wm*64 + i*16 + lg*4;
            const int col = n0 + wn*64 + j*16 + lr;
            const f32x4 v = acc[i][j];
            if (EPI == 1) {
                #pragma unroll
                for (int r = 0; r < 4; r++) {
                    const size_t o = (size_t)(row + r) * N + col;
                    C[o] = res[o] + v[r];
                }
            } else {
                if (col < QKN) {   // Q (scaled) or K
                    const float sc = (col < DEMB) ? 0.125f : 1.0f;
                    #pragma unroll
                    for (int r = 0; r < 4; r++) {
                        const size_t o = (size_t)(row + r) * QKN + col;
                        const float f = v[r] * sc;
                        const __bf16 hb = (__bf16)f;
                        qkh[o] = hb;
                        qkl[o] = (__bf16)(f - (float)hb);
                    }
                } else {           // V -> V^T [ (b*16+h)*64 + d ][ t ]
                    const int d = col - QKN;
                    const int hh = d >> 6, dd = d & 63;
                    const int bb = row >> 11, t = row & 2047;
                    const size_t base = ((size_t)(bb*16 + hh)*64 + dd) * TSEQ + t;
                    #pragma unroll
                    for (int r = 0; r < 4; r++) {
                        const float f = v[r];
                        const __bf16 hb = (__bf16)f;
                        vth[base + r] = hb;
                        vtl[base + r] = (__bf16)(f - (float)hb);
                    }
                }
            }
        }
    }
}

// ---------------- grouped per-expert bf16 GEMM (EPI 2: relu^2; EPI 3: plain) ----------
template<int EPI, int GATHER>
__global__ __launch_bounds__(256) void gemm_moe(const bf16_t* __restrict__ A,
                                                const bf16_t* __restrict__ Ball,
                                                bf16_t* __restrict__ C,
                                                const int* __restrict__ rowmap,
                                                const int* __restrict__ counts,
                                                const int* __restrict__ offs,
                                                int N, int K) {
    const int e = blockIdx.z;
    const int cnt = counts[e];
    if ((int)blockIdx.y * 128 >= cnt) return;
    const int base = offs[e];
    const bf16_t* Bt = Ball + (size_t)e * N * K;
    __shared__ u16 As[128*32];
    __shared__ u16 Bs[128*32];
    const int tid = threadIdx.x;
    const int lane = tid & 63, w = tid >> 6;
    const int lr = lane & 15, lg = lane >> 4;
    const int wm = w >> 1, wn = w & 1;
    const int m0 = blockIdx.y * 128, n0 = blockIdx.x * 128;
    const int rs = tid >> 2, ks = (tid & 3) * 8;
    const int l0 = min(m0 + rs, cnt - 1), l1 = min(m0 + 64 + rs, cnt - 1);
    const size_t r0 = GATHER ? (size_t)rowmap[base + l0] : (size_t)(base + l0);
    const size_t r1 = GATHER ? (size_t)rowmap[base + l1] : (size_t)(base + l1);
    const bf16_t* ga0 = A  + r0 * K + ks;
    const bf16_t* ga1 = A  + r1 * K + ks;
    const bf16_t* gb0 = Bt + (size_t)(n0 + rs)      * K + ks;
    const bf16_t* gb1 = Bt + (size_t)(n0 + 64 + rs) * K + ks;
    char* la0 = (char*)As + tid*16; char* la1 = la0 + 4096;
    char* lb0 = (char*)Bs + tid*16; char* lb1 = lb0 + 4096;
    f32x4 acc[4][4] = {};
    for (int k0 = 0; k0 < K; k0 += 32) {
        __syncthreads();
        gll16(ga0 + k0, la0); gll16(ga1 + k0, la1);
        gll16(gb0 + k0, lb0); gll16(gb1 + k0, lb1);
        __syncthreads();
        bf16x8 af[4], bfr[4];
        #pragma unroll
        for (int i = 0; i < 4; i++) {
            af[i]  = *(const bf16x8*)&As[(wm*64 + i*16 + lr)*32 + lg*8];
            bfr[i] = *(const bf16x8*)&Bs[(wn*64 + i*16 + lr)*32 + lg*8];
        }
        #pragma unroll
        for (int i = 0; i < 4; i++)
            #pragma unroll
            for (int j = 0; j < 4; j++)
                acc[i][j] = mfma16(af[i], bfr[j], acc[i][j]);
    }
    #pragma unroll
    for (int i = 0; i < 4; i++) {
        #pragma unroll
        for (int j = 0; j < 4; j++) {
            const int rowl = m0 + wm*64 + i*16 + lg*4;
            const int col  = n0 + wn*64 + j*16 + lr;
            const f32x4 v = acc[i][j];
            #pragma unroll
            for (int r = 0; r < 4; r++) {
                if (rowl + r < cnt) {
                    float xv = v[r];
                    if (EPI == 2) { xv = fmaxf(xv, 0.f); xv = xv * xv; }
                    C[(size_t)(base + rowl + r) * N + col] = (__bf16)xv;
                }
            }
        }
    }
}

// ---------------- split-bf16 MFMA flash attention, causal, balanced pairs ----------------
// grid (16,16,2): block handles q-tiles qa=bx and qb=31-bx (64 rows each) in ONE kv sweep.
// 4 waves x 16 q-rows per tile. K from qk buffer; V^T pre-transposed in global.
__global__ __launch_bounds__(256) void attn_mfma(const bf16_t* __restrict__ qkh,
                                                 const bf16_t* __restrict__ qkl,
                                                 const bf16_t* __restrict__ vth,
                                                 const bf16_t* __restrict__ vtl,
                                                 bf16_t* __restrict__ aoh,
                                                 bf16_t* __restrict__ aol) {
    __shared__ u16 KsH[64*64];   // [kv][d], chunk-swizzled c^=kv&7
    __shared__ u16 KsL[64*64];
    __shared__ u16 VtH[64*64];   // [d][kv], chunk-swizzled c^=d&7 (src pre-swizzled)
    __shared__ u16 VtL[64*64];
    __shared__ u16 P_H[4*16*72]; // per-wave P / output bounce
    __shared__ u16 P_L[4*16*72];
    const int tid = threadIdx.x, lane = tid & 63, wv = tid >> 6;
    const int lr = lane & 15, lg = lane >> 4;
    const int h = blockIdx.y, b = blockIdx.z;
    const int qa = blockIdx.x, qb = 31 - qa;
    u16* plwH = P_H + wv * 16 * 72;
    u16* plwL = P_L + wv * 16 * 72;
    const int wq0A = qa*64 + wv*16;
    const int wq0B = qb*64 + wv*16;

    bf16x8 qAh[2], qAl[2], qBh[2], qBl[2];
    #pragma unroll
    for (int kf = 0; kf < 2; kf++) {
        const size_t qoA = (size_t)(b*TSEQ + wq0A + lr)*QKN + h*64 + kf*32 + lg*8;
        const size_t qoB = (size_t)(b*TSEQ + wq0B + lr)*QKN + h*64 + kf*32 + lg*8;
        qAh[kf] = *(const bf16x8*)(qkh + qoA);
        qAl[kf] = *(const bf16x8*)(qkl + qoA);
        qBh[kf] = *(const bf16x8*)(qkh + qoB);
        qBl[kf] = *(const bf16x8*)(qkl + qoB);
    }

    f32x4 ofA[4] = {}, ofB[4] = {};
    float mA = -1e30f, lA = 0.f, mB = -1e30f, lB = 0.f;

    const int skv = tid >> 3;                 // 0..31
    const int pst = tid & 7;
    const int chs = pst ^ (skv & 7);          // swizzled source chunk (K and V^T alike)
    const int bh = b*16 + h;
    const bf16_t* kh = qkh + 1024;
    const bf16_t* kl = qkl + 1024;
    const size_t vrow0 = (size_t)(bh*64 + skv)      * TSEQ;
    const size_t vrow1 = (size_t)(bh*64 + skv + 32) * TSEQ;

    auto step = [&](f32x4 (&of)[4], float& mrun, float& lrun,
                    const bf16x8 (&qfh)[2], const bf16x8 (&qfl)[2],
                    const int wq0, const bool diag, const int kvb) {
        f32x4 sf[4] = {};
        #pragma unroll
        for (int kf = 0; kf < 2; kf++)
            #pragma unroll
            for (int f = 0; f < 4; f++) {
                const int idx = (f*16 + lr)*64 + ((kf*32 + lg*8) ^ ((lr & 7) << 3));
                const bf16x8 ah = *(const bf16x8*)&KsH[idx];
                const bf16x8 al = *(const bf16x8*)&KsL[idx];
                sf[f] = mfma16(ah, qfh[kf], sf[f]);
                sf[f] = mfma16(ah, qfl[kf], sf[f]);
                sf[f] = mfma16(al, qfh[kf], sf[f]);
            }
        if (diag) {
            #pragma unroll
            for (int f = 0; f < 4; f++)
                #pragma unroll
                for (int r = 0; r < 4; r++)
                    if (kvb + f*16 + lg*4 + r > wq0 + lr) sf[f][r] = -1e30f;
        }
        float tm = -1e30f;
        #pragma unroll
        for (int f = 0; f < 4; f++)
            tm = fmaxf(tm, fmaxf(fmaxf(sf[f][0], sf[f][1]), fmaxf(sf[f][2], sf[f][3])));
        tm = fmaxf(tm, __shfl_xor(tm, 16));
        tm = fmaxf(tm, __shfl_xor(tm, 32));
        const float mnew = fmaxf(mrun, tm);
        const float fac = __expf(mrun - mnew);
        mrun = mnew;
        float ps = 0.f;
        #pragma unroll
        for (int f = 0; f < 4; f++) {
            float p[4];
            #pragma unroll
            for (int r = 0; r < 4; r++) { p[r] = __expf(sf[f][r] - mnew); ps += p[r]; }
            u16 hb4[4], lb4[4];
            #pragma unroll
            for (int r = 0; r < 4; r++) {
                const __bf16 hb = (__bf16)p[r];
                hb4[r] = f2bf(p[r]);
                lb4[r] = f2bf(p[r] - (float)hb);
            }
            u32* pwh = (u32*)&plwH[lr*72 + f*16 + lg*4];
            u32* pwl = (u32*)&plwL[lr*72 + f*16 + lg*4];
            pwh[0] = (u32)hb4[0] | ((u32)hb4[1] << 16);
            pwh[1] = (u32)hb4[2] | ((u32)hb4[3] << 16);
            pwl[0] = (u32)lb4[0] | ((u32)lb4[1] << 16);
            pwl[1] = (u32)lb4[2] | ((u32)lb4[3] << 16);
        }
        ps += __shfl_xor(ps, 16);
        ps += __shfl_xor(ps, 32);
        lrun = lrun*fac + ps;
        #pragma unroll
        for (int f2 = 0; f2 < 4; f2++)
            #pragma unroll
            for (int r = 0; r < 4; r++) of[f2][r] *= fac;
        #pragma unroll
        for (int hf = 0; hf < 2; hf++) {
            const bf16x8 pbh = *(const bf16x8*)&plwH[lr*72 + hf*32 + lg*8];
            const bf16x8 pbl = *(const bf16x8*)&plwL[lr*72 + hf*32 + lg*8];
            #pragma unroll
            for (int f2 = 0; f2 < 4; f2++) {
                const int vidx = (f2*16 + lr)*64 + (((hf*4 + lg) ^ (lr & 7)) << 3);
                const bf16x8 vah = *(const bf16x8*)&VtH[vidx];
                const bf16x8 val = *(const bf16x8*)&VtL[vidx];
                of[f2] = mfma16(vah, pbh, of[f2]);
                of[f2] = mfma16(vah, pbl, of[f2]);
                of[f2] = mfma16(val, pbh, of[f2]);
            }
        }
    };

    for (int kt = 0; kt <= qb; kt++) {
        __syncthreads();
        const size_t krow = (size_t)(b*TSEQ + kt*64 + skv)*QKN + h*64;
        gll16(kh + krow + chs*8,                     (char*)KsH + tid*16);
        gll16(kh + krow + (size_t)32*QKN + chs*8,    (char*)KsH + 4096 + tid*16);
        gll16(kl + krow + chs*8,                     (char*)KsL + tid*16);
        gll16(kl + krow + (size_t)32*QKN + chs*8,    (char*)KsL + 4096 + tid*16);
        gll16(vth + vrow0 + kt*64 + chs*8,           (char*)VtH + tid*16);
        gll16(vth + vrow1 + kt*64 + chs*8,           (char*)VtH + 4096 + tid*16);
        gll16(vtl + vrow0 + kt*64 + chs*8,           (char*)VtL + tid*16);
        gll16(vtl + vrow1 + kt*64 + chs*8,           (char*)VtL + 4096 + tid*16);
        __syncthreads();
        if (kt <= qa) step(ofA, mA, lA, qAh, qAl, wq0A, kt == qa, kt*64);
        step(ofB, mB, lB, qBh, qBl, wq0B, kt == qb, kt*64);
    }

    // epilogue per tile: normalize, split, bounce through per-wave LDS, coalesced store
    const float invA = 1.f / lA, invB = 1.f / lB;
    #pragma unroll
    for (int f2 = 0; f2 < 4; f2++) {
        u16 hb4[4], lb4[4];
        #pragma unroll
        for (int r = 0; r < 4; r++) {
            const float f = ofA[f2][r] * invA;
            const __bf16 hb = (__bf16)f;
            hb4[r] = f2bf(f);
            lb4[r] = f2bf(f - (float)hb);
        }
        u32* pwh = (u32*)&plwH[lr*72 + f2*16 + lg*4];
        u32* pwl = (u32*)&plwL[lr*72 + f2*16 + lg*4];
        pwh[0] = (u32)hb4[0] | ((u32)hb4[1] << 16);
        pwh[1] = (u32)hb4[2] | ((u32)hb4[3] << 16);
        pwl[0] = (u32)lb4[0] | ((u32)lb4[1] << 16);
        pwl[1] = (u32)lb4[2] | ((u32)lb4[3] << 16);
    }
    asm volatile("s_waitcnt lgkmcnt(0)" ::: "memory");
    __builtin_amdgcn_sched_barrier(0);
    #pragma unroll
    for (int pass = 0; pass < 2; pass++) {
        const int qlr = pass*8 + (lane >> 3);
        const int ch = (lane & 7) * 8;
        const bf16x8 oh = *(const bf16x8*)&plwH[qlr*72 + ch];
        const bf16x8 ol = *(const bf16x8*)&plwL[qlr*72 + ch];
        const size_t go = (size_t)(b*TSEQ + wq0A + qlr) * DEMB + h*64 + ch;
        *(bf16x8*)(aoh + go) = oh;
        *(bf16x8*)(aol + go) = ol;
    }
    asm volatile("s_waitcnt lgkmcnt(0)" ::: "memory");
    __builtin_amdgcn_sched_barrier(0);
    #pragma unroll
    for (int f2 = 0; f2 < 4; f2++) {
        u16 hb4[4], lb4[4];
        #pragma unroll
        for (int r = 0; r < 4; r++) {
            const float f = ofB[f2][r] * invB;
            const __bf16 hb = (__bf16)f;
            hb4[r] = f2bf(f);
            lb4[r] = f2bf(f - (float)hb);
        }
        u32* pwh = (u32*)&plwH[lr*72 + f2*16 + lg*4];
        u32* pwl = (u32*)&plwL[lr*72 + f2*16 + lg*4];
        pwh[0] = (u32)hb4[0] | ((u32)hb4[1] << 16);
        pwh[1] = (u32)hb4[2] | ((u32)hb4[3] << 16);
        pwl[0] = (u32)lb4[0] | ((u32)lb4[1] << 16);
        pwl[1] = (u32)lb4[2] | ((u32)lb4[3] << 16);
    }
    asm volatile("s_waitcnt lgkmcnt(0)" ::: "memory");
    __builtin_amdgcn_sched_barrier(0);
    #pragma unroll
    for (int pass = 0; pass < 2; pass++) {
        const int qlr = pass*8 + (lane >> 3);
        const int ch = (lane & 7) * 8;
        const bf16x8 oh = *(const bf16x8*)&plwH[qlr*72 + ch];
        const bf16x8 ol = *(const bf16x8*)&plwL[qlr*72 + ch];
        const size_t go = (size_t)(b*TSEQ + wq0B + qlr) * DEMB + h*64 + ch;
        *(bf16x8*)(aoh + go) = oh;
        *(bf16x8*)(aol + go) = ol;
    }
}

// ---------------- MoE routing (fp32, rmsnorm folded in) ----------------
__global__ void zero8(int* c) { if (threadIdx.x < NEXP) c[threadIdx.x] = 0; }

__global__ __launch_bounds__(256) void router_k(const float* __restrict__ xout,
                                                const float* __restrict__ rw,
                                                int* __restrict__ idx,
                                                float* __restrict__ wts,
                                                int* __restrict__ pos,
                                                int* __restrict__ counts) {
    const int tok = blockIdx.x * 4 + (threadIdx.x >> 6);
    const int lane = threadIdx.x & 63;
    const float* xr = xout + (size_t)tok * DEMB;
    float ss = 0.f;
    float acc[NEXP];
    #pragma unroll
    for (int e = 0; e < NEXP; e++) acc[e] = 0.f;
    for (int kk = lane; kk < DEMB; kk += 64) {
        const float xv = xr[kk];
        ss += xv * xv;
        #pragma unroll
        for (int e = 0; e < NEXP; e++) acc[e] += xv * rw[kk*NEXP + e];
    }
    #pragma unroll
    for (int off = 32; off; off >>= 1) ss += __shfl_xor(ss, off);
    #pragma unroll
    for (int e = 0; e < NEXP; e++) {
        #pragma unroll
        for (int off = 32; off; off >>= 1) acc[e] += __shfl_xor(acc[e], off);
    }
    if (lane == 0) {
        const float r = rsqrtf(ss * (1.0f/DEMB) + 1e-5f);
        float v[NEXP];
        #pragma unroll
        for (int e = 0; e < NEXP; e++) v[e] = acc[e] * r;
        int b0 = 0; float v0 = v[0];
        #pragma unroll
        for (int e = 1; e < NEXP; e++) if (v[e] > v0) { v0 = v[e]; b0 = e; }
        int b1 = -1; float v1 = -1e30f;
        #pragma unroll
        for (int e = 0; e < NEXP; e++) if (e != b0 && v[e] > v1) { v1 = v[e]; b1 = e; }
        const float w0 = 1.f / (1.f + __expf(v1 - v0));
        idx[tok*2+0] = b0; idx[tok*2+1] = b1;
        wts[tok*2+0] = w0; wts[tok*2+1] = 1.f - w0;
        pos[tok*2+0] = atomicAdd(&counts[b0], 1);
        pos[tok*2+1] = atomicAdd(&counts[b1], 1);
    }
}

__global__ void offsets_k(const int* __restrict__ counts, int* __restrict__ offs) {
    if (threadIdx.x == 0) {
        int s = 0;
        for (int e = 0; e < NEXP; e++) { offs[e] = s; s += counts[e]; }
    }
}

__global__ __launch_bounds__(256) void buildmap_k(const int* __restrict__ idx,
                                                  const int* __restrict__ pos,
                                                  const int* __restrict__ offs,
                                                  int* __restrict__ rowmap,
                                                  int* __restrict__ rowpos) {
    const int n = blockIdx.x * 256 + threadIdx.x;
    #pragma unroll
    for (int s = 0; s < 2; s++) {
        const int e = idx[n*2+s];
        const int r = offs[e] + pos[n*2+s];
        rowmap[r] = n;
        rowpos[n*2+s] = r;
    }
}

__global__ __launch_bounds__(256) void combine_k(const bf16_t* __restrict__ oe,
                                                 const int* __restrict__ rowpos,
                                                 const float* __restrict__ wts,
                                                 float* __restrict__ out) {
    const int n = blockIdx.x;
    const int r0 = rowpos[n*2+0], r1 = rowpos[n*2+1];
    const float w0 = wts[n*2+0], w1 = wts[n*2+1];
    const int c = threadIdx.x * 4;
    const bf16x4 a  = *(const bf16x4*)(oe + (size_t)r0*DEMB + c);
    const bf16x4 b4 = *(const bf16x4*)(oe + (size_t)r1*DEMB + c);
    float4* op = (float4*)(out + (size_t)n*DEMB + c);
    float4 o = *op;
    o.x += w0*(float)a[0] + w1*(float)b4[0];
    o.y += w0*(float)a[1] + w1*(float)b4[1];
    o.z += w0*(float)a[2] + w1*(float)b4[2];
    o.w += w0*(float)a[3] + w1*(float)b4[3];
    *op = o;
}

extern "C" void kernel_launch(void* const* d_in, const int* in_sizes, int n_in,
                              void* d_out, int out_size, void* d_ws, size_t ws_size,
                              hipStream_t stream) {
    (void)in_sizes; (void)n_in; (void)out_size; (void)ws_size;
    const float* x   = (const float*)d_in[0];
    const float* wq  = (const float*)d_in[1];
    const float* wk  = (const float*)d_in[2];
    const float* wv  = (const float*)d_in[3];
    const float* wo  = (const float*)d_in[4];
    const float* rw  = (const float*)d_in[5];
    const float* fc1 = (const float*)d_in[6];
    const float* fc2 = (const float*)d_in[7];
    float* out = (float*)d_out;
    char* ws = (char*)d_ws;
    const size_t MB = 1024*1024;

    // region map (MB), phase-overlaid:
    //  0-16 : wqkv_h(6) wqkv_l(6) wo_h(2) wo_l(2) [prep->WO]  -> oe(16) [moe2->combine]
    // 16-64 : qk_h(16)@16 qk_l(16)@32 vt_h(8)@48 vt_l(8)@56 [QKV->attn/WO]
    //         -> fc1_t(32)@16, fc2_t(32)@48 [post-WO -> moe]
    // 64-80 : h_hi(8) h_lo(8) [rms1->QKV]  -> ao_h(8) ao_l(8) [attn->WO]
    // 80-88 : h bf16 (rms2 out)  [->moe1]
    // 88-120: h1 bf16 (32)       [moe1->moe2]
    // 120+  : meta
    bf16_t* wqkv_h = (bf16_t*)(ws);
    bf16_t* wqkv_l = (bf16_t*)(ws + 6*MB);
    bf16_t* wo_h   = (bf16_t*)(ws + 12*MB);
    bf16_t* wo_l   = (bf16_t*)(ws + 14*MB);
    bf16_t* qk_h   = (bf16_t*)(ws + 16*MB);
    bf16_t* qk_l   = (bf16_t*)(ws + 32*MB);
    bf16_t* vt_h   = (bf16_t*)(ws + 48*MB);
    bf16_t* vt_l   = (bf16_t*)(ws + 56*MB);
    bf16_t* fc1_t  = (bf16_t*)(ws + 16*MB);
    bf16_t* fc2_t  = (bf16_t*)(ws + 48*MB);
    bf16_t* h_hi   = (bf16_t*)(ws + 64*MB);
    bf16_t* h_lo   = (bf16_t*)(ws + 72*MB);
    bf16_t* ao_h   = (bf16_t*)(ws + 64*MB);
    bf16_t* ao_l   = (bf16_t*)(ws + 72*MB);
    bf16_t* h      = (bf16_t*)(ws + 80*MB);
    bf16_t* h1     = (bf16_t*)(ws + 88*MB);
    bf16_t* oe     = (bf16_t*)(ws);
    char* meta = ws + 120*MB;
    int*   idx    = (int*)(meta);
    int*   pos    = (int*)(meta + 64*1024);
    int*   rowmap = (int*)(meta + 128*1024);
    int*   rowpos = (int*)(meta + 192*1024);
    float* wts    = (float*)(meta + 256*1024);
    int*   counts = (int*)(meta + 320*1024);
    int*   offs   = (int*)(meta + 320*1024 + 256);

    const dim3 blk(256);

    // ---- attention path ----
    transp_split_k<<<dim3(32,32), blk, 0, stream>>>(wq, wqkv_h,               wqkv_l,               1024, 1024);
    transp_split_k<<<dim3(32,32), blk, 0, stream>>>(wk, wqkv_h + 1024*1024,   wqkv_l + 1024*1024,   1024, 1024);
    transp_split_k<<<dim3(32,32), blk, 0, stream>>>(wv, wqkv_h + 2*1024*1024, wqkv_l + 2*1024*1024, 1024, 1024);
    transp_split_k<<<dim3(32,32), blk, 0, stream>>>(wo, wo_h,                 wo_l,                 1024, 1024);
    rmsnorm_split_k<<<NTOK, blk, 0, stream>>>(x, h_hi, h_lo);
    gemm_split<3><<<dim3(QKVS/128, NTOK/128), blk, 0, stream>>>(
        h_hi, h_lo, wqkv_h, wqkv_l, nullptr, nullptr, qk_h, qk_l, vt_h, vt_l, QKVS, 1024);
    attn_mfma<<<dim3(16, 16, 2), blk, 0, stream>>>(qk_h, qk_l, vt_h, vt_l, ao_h, ao_l);
    gemm_split<1><<<dim3(DEMB/128, NTOK/128), blk, 0, stream>>>(
        ao_h, ao_l, wo_h, wo_l, x, out, nullptr, nullptr, nullptr, nullptr, DEMB, 1024);

    // ---- MoE path (fp32 router, bf16 experts) ----
    transp_k<<<dim3(64,32,8), blk, 0, stream>>>(fc1, fc1_t, 1024, 2048);
    transp_k<<<dim3(32,64,8), blk, 0, stream>>>(fc2, fc2_t, 2048, 1024);
    rmsnorm_bf_k<<<NTOK, blk, 0, stream>>>(out, h);
    zero8<<<1, 64, 0, stream>>>(counts);
    router_k<<<NTOK/4, blk, 0, stream>>>(out, rw, idx, wts, pos, counts);
    offsets_k<<<1, 64, 0, stream>>>(counts, offs);
    buildmap_k<<<NTOK/256, blk, 0, stream>>>(idx, pos, offs, rowmap, rowpos);
    gemm_moe<2,1><<<dim3(EDIM/128, 32, NEXP), blk, 0, stream>>>(
        h, fc1_t, h1, rowmap, counts, offs, EDIM, 1024);
    gemm_moe<3,0><<<dim3(DEMB/128, 32, NEXP), blk, 0, stream>>>(
        h1, fc2_t, oe, rowmap, counts, offs, DEMB, EDIM);
    combine_k<<<NTOK, blk, 0, stream>>>(oe, rowpos, wts, out);
}

// Round 6
// 545.712 us; speedup vs baseline: 4.9758x; 1.0042x over previous
//
#include <hip/hip_runtime.h>
#include <math.h>

#define NTOK 4096
#define DEMB 1024
#define TSEQ 2048
#define QKVS 3072
#define QKN  2048
#define EDIM 2048
#define NEXP 8

typedef unsigned short u16;
typedef unsigned int u32;
typedef __bf16 bf16_t;
typedef __bf16 bf16x8 __attribute__((ext_vector_type(8)));
typedef __bf16 bf16x4 __attribute__((ext_vector_type(4)));
typedef float f32x4 __attribute__((ext_vector_type(4)));

__device__ __forceinline__ f32x4 mfma16(bf16x8 a, bf16x8 b, f32x4 c) {
    return __builtin_amdgcn_mfma_f32_16x16x32_bf16(a, b, c, 0, 0, 0);
}
__device__ __forceinline__ void gll16(const void* g, void* l) {
    __builtin_amdgcn_global_load_lds((const __attribute__((address_space(1))) u32*)g,
                                     (__attribute__((address_space(3))) u32*)l, 16, 0, 0);
}
__device__ __forceinline__ u16 f2bf(float x) {
    union { __bf16 h; u16 u; } c; c.h = (__bf16)x; return c.u;
}

// ---------------- rmsnorm fp32 -> split bf16 (hi, lo) ----------------
__global__ __launch_bounds__(256) void rmsnorm_split_k(const float* __restrict__ x,
                                                       bf16_t* __restrict__ hi,
                                                       bf16_t* __restrict__ lo) {
    const int row = blockIdx.x;
    const float4 v = ((const float4*)(x + (size_t)row * DEMB))[threadIdx.x];
    float ss = v.x*v.x + v.y*v.y + v.z*v.z + v.w*v.w;
    #pragma unroll
    for (int off = 32; off; off >>= 1) ss += __shfl_xor(ss, off);
    __shared__ float wsum[4];
    if ((threadIdx.x & 63) == 0) wsum[threadIdx.x >> 6] = ss;
    __syncthreads();
    const float r = rsqrtf((wsum[0]+wsum[1]+wsum[2]+wsum[3]) * (1.0f/DEMB) + 1e-5f);
    const float f[4] = {v.x*r, v.y*r, v.z*r, v.w*r};
    bf16x4 hv, lv;
    #pragma unroll
    for (int j = 0; j < 4; j++) {
        const __bf16 hb = (__bf16)f[j];
        hv[j] = hb;
        lv[j] = (__bf16)(f[j] - (float)hb);
    }
    ((bf16x4*)(hi + (size_t)row*DEMB))[threadIdx.x] = hv;
    ((bf16x4*)(lo + (size_t)row*DEMB))[threadIdx.x] = lv;
}

// ---------------- rmsnorm fp32 -> plain bf16 ----------------
__global__ __launch_bounds__(256) void rmsnorm_bf_k(const float* __restrict__ x,
                                                    bf16_t* __restrict__ y) {
    const int row = blockIdx.x;
    const float4 v = ((const float4*)(x + (size_t)row * DEMB))[threadIdx.x];
    float ss = v.x*v.x + v.y*v.y + v.z*v.z + v.w*v.w;
    #pragma unroll
    for (int off = 32; off; off >>= 1) ss += __shfl_xor(ss, off);
    __shared__ float wsum[4];
    if ((threadIdx.x & 63) == 0) wsum[threadIdx.x >> 6] = ss;
    __syncthreads();
    const float r = rsqrtf((wsum[0]+wsum[1]+wsum[2]+wsum[3]) * (1.0f/DEMB) + 1e-5f);
    bf16x4 o;
    o[0] = (__bf16)(v.x*r); o[1] = (__bf16)(v.y*r);
    o[2] = (__bf16)(v.z*r); o[3] = (__bf16)(v.w*r);
    ((bf16x4*)(y + (size_t)row*DEMB))[threadIdx.x] = o;
}

// ---------------- weight transpose fp32 [K][M] -> split bf16 [M][K] ----------------
__global__ __launch_bounds__(256) void transp_split_k(const float* __restrict__ w,
                                                      bf16_t* __restrict__ wth,
                                                      bf16_t* __restrict__ wtl,
                                                      int K, int M) {
    __shared__ float t[32][33];
    const int m0 = blockIdx.x*32, k0 = blockIdx.y*32;
    const int tx = threadIdx.x & 31, ty = threadIdx.x >> 5;
    #pragma unroll
    for (int i = 0; i < 32; i += 8) t[ty+i][tx] = w[(size_t)(k0+ty+i)*M + m0+tx];
    __syncthreads();
    #pragma unroll
    for (int i = 0; i < 32; i += 8) {
        const float f = t[tx][ty+i];
        const __bf16 hb = (__bf16)f;
        wth[(size_t)(m0+ty+i)*K + k0+tx] = hb;
        wtl[(size_t)(m0+ty+i)*K + k0+tx] = (__bf16)(f - (float)hb);
    }
}

// ---------------- weight transpose fp32 [K][M] -> plain bf16 [M][K] (per expert) ------
__global__ __launch_bounds__(256) void transp_k(const float* __restrict__ w,
                                                bf16_t* __restrict__ wt,
                                                int K, int M) {
    __shared__ float t[32][33];
    const size_t eo = (size_t)blockIdx.z * K * M;
    w += eo; wt += eo;
    const int m0 = blockIdx.x*32, k0 = blockIdx.y*32;
    const int tx = threadIdx.x & 31, ty = threadIdx.x >> 5;
    #pragma unroll
    for (int i = 0; i < 32; i += 8) t[ty+i][tx] = w[(size_t)(k0+ty+i)*M + m0+tx];
    __syncthreads();
    #pragma unroll
    for (int i = 0; i < 32; i += 8) wt[(size_t)(m0+ty+i)*K + k0+tx] = (__bf16)t[tx][ty+i];
}

// ---------------- split-bf16 GEMM: C = (Ah+Al)(Bh+Bl)^T, 3 MFMA products ----
// EPI 1: fp32 store = res + acc
// EPI 3: QKV epilogue -> Q (x0.125) and K split into qk [tok][2048]; V split into V^T [bh*64+d][t]
template<int EPI>
__global__ __launch_bounds__(256) void gemm_split(const bf16_t* __restrict__ Ah,
                                                  const bf16_t* __restrict__ Al,
                                                  const bf16_t* __restrict__ Bh,
                                                  const bf16_t* __restrict__ Bl,
                                                  const float* __restrict__ res,
                                                  float* __restrict__ C,
                                                  bf16_t* __restrict__ qkh,
                                                  bf16_t* __restrict__ qkl,
                                                  bf16_t* __restrict__ vth,
                                                  bf16_t* __restrict__ vtl,
                                                  int N, int K) {
    __shared__ u16 AsH[128*32];
    __shared__ u16 AsL[128*32];
    __shared__ u16 BsH[128*32];
    __shared__ u16 BsL[128*32];
    const int tid = threadIdx.x;
    const int lane = tid & 63, w = tid >> 6;
    const int lr = lane & 15, lg = lane >> 4;
    const int wm = w >> 1, wn = w & 1;
    const int m0 = blockIdx.y * 128, n0 = blockIdx.x * 128;
    const int rs = tid >> 2, ks = (tid & 3) * 8;
    const size_t arow0 = (size_t)(m0 + rs) * K + ks;
    const size_t arow1 = (size_t)(m0 + 64 + rs) * K + ks;
    const size_t brow0 = (size_t)(n0 + rs) * K + ks;
    const size_t brow1 = (size_t)(n0 + 64 + rs) * K + ks;
    char* lah = (char*)AsH + tid*16;
    char* lal = (char*)AsL + tid*16;
    char* lbh = (char*)BsH + tid*16;
    char* lbl = (char*)BsL + tid*16;
    f32x4 acc[4][4] = {};
    for (int k0 = 0; k0 < K; k0 += 32) {
        __syncthreads();
        gll16(Ah + arow0 + k0, lah); gll16(Ah + arow1 + k0, lah + 4096);
        gll16(Al + arow0 + k0, lal); gll16(Al + arow1 + k0, lal + 4096);
        gll16(Bh + brow0 + k0, lbh); gll16(Bh + brow1 + k0, lbh + 4096);
        gll16(Bl + brow0 + k0, lbl); gll16(Bl + brow1 + k0, lbl + 4096);
        __syncthreads();
        bf16x8 ah[4], al[4], bh[4], bl[4];
        #pragma unroll
        for (int i = 0; i < 4; i++) {
            const int ao = (wm*64 + i*16 + lr)*32 + lg*8;
            const int bo = (wn*64 + i*16 + lr)*32 + lg*8;
            ah[i] = *(const bf16x8*)&AsH[ao];
            al[i] = *(const bf16x8*)&AsL[ao];
            bh[i] = *(const bf16x8*)&BsH[bo];
            bl[i] = *(const bf16x8*)&BsL[bo];
        }
        #pragma unroll
        for (int i = 0; i < 4; i++)
            #pragma unroll
            for (int j = 0; j < 4; j++) {
                acc[i][j] = mfma16(ah[i], bh[j], acc[i][j]);
                acc[i][j] = mfma16(ah[i], bl[j], acc[i][j]);
                acc[i][j] = mfma16(al[i], bh[j], acc[i][j]);
            }
    }
    #pragma unroll
    for (int i = 0; i < 4; i++) {
        #pragma unroll
        for (int j = 0; j < 4; j++) {
            const int row = m0 + wm*64 + i*16 + lg*4;
            const int col = n0 + wn*64 + j*16 + lr;
            const f32x4 v = acc[i][j];
            if (EPI == 1) {
                #pragma unroll
                for (int r = 0; r < 4; r++) {
                    const size_t o = (size_t)(row + r) * N + col;
                    C[o] = res[o] + v[r];
                }
            } else {
                if (col < QKN) {   // Q (scaled) or K
                    const float sc = (col < DEMB) ? 0.125f : 1.0f;
                    #pragma unroll
                    for (int r = 0; r < 4; r++) {
                        const size_t o = (size_t)(row + r) * QKN + col;
                        const float f = v[r] * sc;
                        const __bf16 hb = (__bf16)f;
                        qkh[o] = hb;
                        qkl[o] = (__bf16)(f - (float)hb);
                    }
                } else {           // V -> V^T [ (b*16+h)*64 + d ][ t ]
                    const int d = col - QKN;
                    const int hh = d >> 6, dd = d & 63;
                    const int bb = row >> 11, t = row & 2047;
                    const size_t base = ((size_t)(bb*16 + hh)*64 + dd) * TSEQ + t;
                    #pragma unroll
                    for (int r = 0; r < 4; r++) {
                        const float f = v[r];
                        const __bf16 hb = (__bf16)f;
                        vth[base + r] = hb;
                        vtl[base + r] = (__bf16)(f - (float)hb);
                    }
                }
            }
        }
    }
}

// ---------------- grouped per-expert bf16 GEMM (EPI 2: relu^2; EPI 3: plain) ----------
template<int EPI, int GATHER>
__global__ __launch_bounds__(256) void gemm_moe(const bf16_t* __restrict__ A,
                                                const bf16_t* __restrict__ Ball,
                                                bf16_t* __restrict__ C,
                                                const int* __restrict__ rowmap,
                                                const int* __restrict__ counts,
                                                const int* __restrict__ offs,
                                                int N, int K) {
    const int e = blockIdx.z;
    const int cnt = counts[e];
    if ((int)blockIdx.y * 128 >= cnt) return;
    const int base = offs[e];
    const bf16_t* Bt = Ball + (size_t)e * N * K;
    __shared__ u16 As[128*32];
    __shared__ u16 Bs[128*32];
    const int tid = threadIdx.x;
    const int lane = tid & 63, w = tid >> 6;
    const int lr = lane & 15, lg = lane >> 4;
    const int wm = w >> 1, wn = w & 1;
    const int m0 = blockIdx.y * 128, n0 = blockIdx.x * 128;
    const int rs = tid >> 2, ks = (tid & 3) * 8;
    const int l0 = min(m0 + rs, cnt - 1), l1 = min(m0 + 64 + rs, cnt - 1);
    const size_t r0 = GATHER ? (size_t)rowmap[base + l0] : (size_t)(base + l0);
    const size_t r1 = GATHER ? (size_t)rowmap[base + l1] : (size_t)(base + l1);
    const bf16_t* ga0 = A  + r0 * K + ks;
    const bf16_t* ga1 = A  + r1 * K + ks;
    const bf16_t* gb0 = Bt + (size_t)(n0 + rs)      * K + ks;
    const bf16_t* gb1 = Bt + (size_t)(n0 + 64 + rs) * K + ks;
    char* la0 = (char*)As + tid*16; char* la1 = la0 + 4096;
    char* lb0 = (char*)Bs + tid*16; char* lb1 = lb0 + 4096;
    f32x4 acc[4][4] = {};
    for (int k0 = 0; k0 < K; k0 += 32) {
        __syncthreads();
        gll16(ga0 + k0, la0); gll16(ga1 + k0, la1);
        gll16(gb0 + k0, lb0); gll16(gb1 + k0, lb1);
        __syncthreads();
        bf16x8 af[4], bfr[4];
        #pragma unroll
        for (int i = 0; i < 4; i++) {
            af[i]  = *(const bf16x8*)&As[(wm*64 + i*16 + lr)*32 + lg*8];
            bfr[i] = *(const bf16x8*)&Bs[(wn*64 + i*16 + lr)*32 + lg*8];
        }
        #pragma unroll
        for (int i = 0; i < 4; i++)
            #pragma unroll
            for (int j = 0; j < 4; j++)
                acc[i][j] = mfma16(af[i], bfr[j], acc[i][j]);
    }
    #pragma unroll
    for (int i = 0; i < 4; i++) {
        #pragma unroll
        for (int j = 0; j < 4; j++) {
            const int rowl = m0 + wm*64 + i*16 + lg*4;
            const int col  = n0 + wn*64 + j*16 + lr;
            const f32x4 v = acc[i][j];
            #pragma unroll
            for (int r = 0; r < 4; r++) {
                if (rowl + r < cnt) {
                    float xv = v[r];
                    if (EPI == 2) { xv = fmaxf(xv, 0.f); xv = xv * xv; }
                    C[(size_t)(base + rowl + r) * N + col] = (__bf16)xv;
                }
            }
        }
    }
}

// ---------------- split-bf16 MFMA flash attention, causal, balanced pairs ----------------
// grid (16,16,2): block handles q-tiles qa=bx and qb=31-bx (64 rows each) in ONE kv sweep.
// 4 waves x 16 q-rows per tile. K from qk buffer; V^T pre-transposed in global.
__global__ __launch_bounds__(256) void attn_mfma(const bf16_t* __restrict__ qkh,
                                                 const bf16_t* __restrict__ qkl,
                                                 const bf16_t* __restrict__ vth,
                                                 const bf16_t* __restrict__ vtl,
                                                 bf16_t* __restrict__ aoh,
                                                 bf16_t* __restrict__ aol) {
    __shared__ u16 KsH[64*64];   // [kv][d], chunk-swizzled c^=kv&7
    __shared__ u16 KsL[64*64];
    __shared__ u16 VtH[64*64];   // [d][kv], chunk-swizzled c^=d&7 (src pre-swizzled)
    __shared__ u16 VtL[64*64];
    __shared__ u16 P_H[4*16*72]; // per-wave P / output bounce
    __shared__ u16 P_L[4*16*72];
    const int tid = threadIdx.x, lane = tid & 63, wv = tid >> 6;
    const int lr = lane & 15, lg = lane >> 4;
    const int h = blockIdx.y, b = blockIdx.z;
    const int qa = blockIdx.x, qb = 31 - qa;
    u16* plwH = P_H + wv * 16 * 72;
    u16* plwL = P_L + wv * 16 * 72;
    const int wq0A = qa*64 + wv*16;
    const int wq0B = qb*64 + wv*16;

    bf16x8 qAh[2], qAl[2], qBh[2], qBl[2];
    #pragma unroll
    for (int kf = 0; kf < 2; kf++) {
        const size_t qoA = (size_t)(b*TSEQ + wq0A + lr)*QKN + h*64 + kf*32 + lg*8;
        const size_t qoB = (size_t)(b*TSEQ + wq0B + lr)*QKN + h*64 + kf*32 + lg*8;
        qAh[kf] = *(const bf16x8*)(qkh + qoA);
        qAl[kf] = *(const bf16x8*)(qkl + qoA);
        qBh[kf] = *(const bf16x8*)(qkh + qoB);
        qBl[kf] = *(const bf16x8*)(qkl + qoB);
    }

    f32x4 ofA[4] = {}, ofB[4] = {};
    float mA = -1e30f, lA = 0.f, mB = -1e30f, lB = 0.f;

    const int skv = tid >> 3;                 // 0..31
    const int pst = tid & 7;
    const int chs = pst ^ (skv & 7);          // swizzled source chunk (K and V^T alike)
    const int bh = b*16 + h;
    const bf16_t* kh = qkh + 1024;
    const bf16_t* kl = qkl + 1024;
    const size_t vrow0 = (size_t)(bh*64 + skv)      * TSEQ;
    const size_t vrow1 = (size_t)(bh*64 + skv + 32) * TSEQ;

    auto step = [&](f32x4 (&of)[4], float& mrun, float& lrun,
                    const bf16x8 (&qfh)[2], const bf16x8 (&qfl)[2],
                    const int wq0, const bool diag, const int kvb) {
        f32x4 sf[4] = {};
        #pragma unroll
        for (int kf = 0; kf < 2; kf++)
            #pragma unroll
            for (int f = 0; f < 4; f++) {
                const int idx = (f*16 + lr)*64 + ((kf*32 + lg*8) ^ ((lr & 7) << 3));
                const bf16x8 ah = *(const bf16x8*)&KsH[idx];
                const bf16x8 al = *(const bf16x8*)&KsL[idx];
                sf[f] = mfma16(ah, qfh[kf], sf[f]);
                sf[f] = mfma16(ah, qfl[kf], sf[f]);
                sf[f] = mfma16(al, qfh[kf], sf[f]);
            }
        if (diag) {
            #pragma unroll
            for (int f = 0; f < 4; f++)
                #pragma unroll
                for (int r = 0; r < 4; r++)
                    if (kvb + f*16 + lg*4 + r > wq0 + lr) sf[f][r] = -1e30f;
        }
        float tm = -1e30f;
        #pragma unroll
        for (int f = 0; f < 4; f++)
            tm = fmaxf(tm, fmaxf(fmaxf(sf[f][0], sf[f][1]), fmaxf(sf[f][2], sf[f][3])));
        tm = fmaxf(tm, __shfl_xor(tm, 16));
        tm = fmaxf(tm, __shfl_xor(tm, 32));
        const float mnew = fmaxf(mrun, tm);
        const float fac = __expf(mrun - mnew);
        mrun = mnew;
        float ps = 0.f;
        #pragma unroll
        for (int f = 0; f < 4; f++) {
            float p[4];
            #pragma unroll
            for (int r = 0; r < 4; r++) { p[r] = __expf(sf[f][r] - mnew); ps += p[r]; }
            u16 hb4[4], lb4[4];
            #pragma unroll
            for (int r = 0; r < 4; r++) {
                const __bf16 hb = (__bf16)p[r];
                hb4[r] = f2bf(p[r]);
                lb4[r] = f2bf(p[r] - (float)hb);
            }
            u32* pwh = (u32*)&plwH[lr*72 + f*16 + lg*4];
            u32* pwl = (u32*)&plwL[lr*72 + f*16 + lg*4];
            pwh[0] = (u32)hb4[0] | ((u32)hb4[1] << 16);
            pwh[1] = (u32)hb4[2] | ((u32)hb4[3] << 16);
            pwl[0] = (u32)lb4[0] | ((u32)lb4[1] << 16);
            pwl[1] = (u32)lb4[2] | ((u32)lb4[3] << 16);
        }
        ps += __shfl_xor(ps, 16);
        ps += __shfl_xor(ps, 32);
        lrun = lrun*fac + ps;
        #pragma unroll
        for (int f2 = 0; f2 < 4; f2++)
            #pragma unroll
            for (int r = 0; r < 4; r++) of[f2][r] *= fac;
        #pragma unroll
        for (int hf = 0; hf < 2; hf++) {
            const bf16x8 pbh = *(const bf16x8*)&plwH[lr*72 + hf*32 + lg*8];
            const bf16x8 pbl = *(const bf16x8*)&plwL[lr*72 + hf*32 + lg*8];
            #pragma unroll
            for (int f2 = 0; f2 < 4; f2++) {
                const int vidx = (f2*16 + lr)*64 + (((hf*4 + lg) ^ (lr & 7)) << 3);
                const bf16x8 vah = *(const bf16x8*)&VtH[vidx];
                const bf16x8 val = *(const bf16x8*)&VtL[vidx];
                of[f2] = mfma16(vah, pbh, of[f2]);
                of[f2] = mfma16(vah, pbl, of[f2]);
                of[f2] = mfma16(val, pbh, of[f2]);
            }
        }
    };

    for (int kt = 0; kt <= qb; kt++) {
        __syncthreads();
        const size_t krow = (size_t)(b*TSEQ + kt*64 + skv)*QKN + h*64;
        gll16(kh + krow + chs*8,                     (char*)KsH + tid*16);
        gll16(kh + krow + (size_t)32*QKN + chs*8,    (char*)KsH + 4096 + tid*16);
        gll16(kl + krow + chs*8,                     (char*)KsL + tid*16);
        gll16(kl + krow + (size_t)32*QKN + chs*8,    (char*)KsL + 4096 + tid*16);
        gll16(vth + vrow0 + kt*64 + chs*8,           (char*)VtH + tid*16);
        gll16(vth + vrow1 + kt*64 + chs*8,           (char*)VtH + 4096 + tid*16);
        gll16(vtl + vrow0 + kt*64 + chs*8,           (char*)VtL + tid*16);
        gll16(vtl + vrow1 + kt*64 + chs*8,           (char*)VtL + 4096 + tid*16);
        __syncthreads();
        if (kt <= qa) step(ofA, mA, lA, qAh, qAl, wq0A, kt == qa, kt*64);
        step(ofB, mB, lB, qBh, qBl, wq0B, kt == qb, kt*64);
    }

    // epilogue per tile: normalize, split, bounce through per-wave LDS, coalesced store
    const float invA = 1.f / lA, invB = 1.f / lB;
    #pragma unroll
    for (int f2 = 0; f2 < 4; f2++) {
        u16 hb4[4], lb4[4];
        #pragma unroll
        for (int r = 0; r < 4; r++) {
            const float f = ofA[f2][r] * invA;
            const __bf16 hb = (__bf16)f;
            hb4[r] = f2bf(f);
            lb4[r] = f2bf(f - (float)hb);
        }
        u32* pwh = (u32*)&plwH[lr*72 + f2*16 + lg*4];
        u32* pwl = (u32*)&plwL[lr*72 + f2*16 + lg*4];
        pwh[0] = (u32)hb4[0] | ((u32)hb4[1] << 16);
        pwh[1] = (u32)hb4[2] | ((u32)hb4[3] << 16);
        pwl[0] = (u32)lb4[0] | ((u32)lb4[1] << 16);
        pwl[1] = (u32)lb4[2] | ((u32)lb4[3] << 16);
    }
    asm volatile("s_waitcnt lgkmcnt(0)" ::: "memory");
    __builtin_amdgcn_sched_barrier(0);
    #pragma unroll
    for (int pass = 0; pass < 2; pass++) {
        const int qlr = pass*8 + (lane >> 3);
        const int ch = (lane & 7) * 8;
        const bf16x8 oh = *(const bf16x8*)&plwH[qlr*72 + ch];
        const bf16x8 ol = *(const bf16x8*)&plwL[qlr*72 + ch];
        const size_t go = (size_t)(b*TSEQ + wq0A + qlr) * DEMB + h*64 + ch;
        *(bf16x8*)(aoh + go) = oh;
        *(bf16x8*)(aol + go) = ol;
    }
    asm volatile("s_waitcnt lgkmcnt(0)" ::: "memory");
    __builtin_amdgcn_sched_barrier(0);
    #pragma unroll
    for (int f2 = 0; f2 < 4; f2++) {
        u16 hb4[4], lb4[4];
        #pragma unroll
        for (int r = 0; r < 4; r++) {
            const float f = ofB[f2][r] * invB;
            const __bf16 hb = (__bf16)f;
            hb4[r] = f2bf(f);
            lb4[r] = f2bf(f - (float)hb);
        }
        u32* pwh = (u32*)&plwH[lr*72 + f2*16 + lg*4];
        u32* pwl = (u32*)&plwL[lr*72 + f2*16 + lg*4];
        pwh[0] = (u32)hb4[0] | ((u32)hb4[1] << 16);
        pwh[1] = (u32)hb4[2] | ((u32)hb4[3] << 16);
        pwl[0] = (u32)lb4[0] | ((u32)lb4[1] << 16);
        pwl[1] = (u32)lb4[2] | ((u32)lb4[3] << 16);
    }
    asm volatile("s_waitcnt lgkmcnt(0)" ::: "memory");
    __builtin_amdgcn_sched_barrier(0);
    #pragma unroll
    for (int pass = 0; pass < 2; pass++) {
        const int qlr = pass*8 + (lane >> 3);
        const int ch = (lane & 7) * 8;
        const bf16x8 oh = *(const bf16x8*)&plwH[qlr*72 + ch];
        const bf16x8 ol = *(const bf16x8*)&plwL[qlr*72 + ch];
        const size_t go = (size_t)(b*TSEQ + wq0B + qlr) * DEMB + h*64 + ch;
        *(bf16x8*)(aoh + go) = oh;
        *(bf16x8*)(aol + go) = ol;
    }
}

// ---------------- MoE routing (fp32, rmsnorm folded in) ----------------
__global__ void zero8(int* c) { if (threadIdx.x < NEXP) c[threadIdx.x] = 0; }

__global__ __launch_bounds__(256) void router_k(const float* __restrict__ xout,
                                                const float* __restrict__ rw,
                                                int* __restrict__ idx,
                                                float* __restrict__ wts,
                                                int* __restrict__ pos,
                                                int* __restrict__ counts) {
    const int tok = blockIdx.x * 4 + (threadIdx.x >> 6);
    const int lane = threadIdx.x & 63;
    const float* xr = xout + (size_t)tok * DEMB;
    float ss = 0.f;
    float acc[NEXP];
    #pragma unroll
    for (int e = 0; e < NEXP; e++) acc[e] = 0.f;
    for (int kk = lane; kk < DEMB; kk += 64) {
        const float xv = xr[kk];
        ss += xv * xv;
        #pragma unroll
        for (int e = 0; e < NEXP; e++) acc[e] += xv * rw[kk*NEXP + e];
    }
    #pragma unroll
    for (int off = 32; off; off >>= 1) ss += __shfl_xor(ss, off);
    #pragma unroll
    for (int e = 0; e < NEXP; e++) {
        #pragma unroll
        for (int off = 32; off; off >>= 1) acc[e] += __shfl_xor(acc[e], off);
    }
    if (lane == 0) {
        const float r = rsqrtf(ss * (1.0f/DEMB) + 1e-5f);
        float v[NEXP];
        #pragma unroll
        for (int e = 0; e < NEXP; e++) v[e] = acc[e] * r;
        int b0 = 0; float v0 = v[0];
        #pragma unroll
        for (int e = 1; e < NEXP; e++) if (v[e] > v0) { v0 = v[e]; b0 = e; }
        int b1 = -1; float v1 = -1e30f;
        #pragma unroll
        for (int e = 0; e < NEXP; e++) if (e != b0 && v[e] > v1) { v1 = v[e]; b1 = e; }
        const float w0 = 1.f / (1.f + __expf(v1 - v0));
        idx[tok*2+0] = b0; idx[tok*2+1] = b1;
        wts[tok*2+0] = w0; wts[tok*2+1] = 1.f - w0;
        pos[tok*2+0] = atomicAdd(&counts[b0], 1);
        pos[tok*2+1] = atomicAdd(&counts[b1], 1);
    }
}

__global__ void offsets_k(const int* __restrict__ counts, int* __restrict__ offs) {
    if (threadIdx.x == 0) {
        int s = 0;
        for (int e = 0; e < NEXP; e++) { offs[e] = s; s += counts[e]; }
    }
}

__global__ __launch_bounds__(256) void buildmap_k(const int* __restrict__ idx,
                                                  const int* __restrict__ pos,
                                                  const int* __restrict__ offs,
                                                  int* __restrict__ rowmap,
                                                  int* __restrict__ rowpos) {
    const int n = blockIdx.x * 256 + threadIdx.x;
    #pragma unroll
    for (int s = 0; s < 2; s++) {
        const int e = idx[n*2+s];
        const int r = offs[e] + pos[n*2+s];
        rowmap[r] = n;
        rowpos[n*2+s] = r;
    }
}

__global__ __launch_bounds__(256) void combine_k(const bf16_t* __restrict__ oe,
                                                 const int* __restrict__ rowpos,
                                                 const float* __restrict__ wts,
                                                 float* __restrict__ out) {
    const int n = blockIdx.x;
    const int r0 = rowpos[n*2+0], r1 = rowpos[n*2+1];
    const float w0 = wts[n*2+0], w1 = wts[n*2+1];
    const int c = threadIdx.x * 4;
    const bf16x4 a  = *(const bf16x4*)(oe + (size_t)r0*DEMB + c);
    const bf16x4 b4 = *(const bf16x4*)(oe + (size_t)r1*DEMB + c);
    float4* op = (float4*)(out + (size_t)n*DEMB + c);
    float4 o = *op;
    o.x += w0*(float)a[0] + w1*(float)b4[0];
    o.y += w0*(float)a[1] + w1*(float)b4[1];
    o.z += w0*(float)a[2] + w1*(float)b4[2];
    o.w += w0*(float)a[3] + w1*(float)b4[3];
    *op = o;
}

extern "C" void kernel_launch(void* const* d_in, const int* in_sizes, int n_in,
                              void* d_out, int out_size, void* d_ws, size_t ws_size,
                              hipStream_t stream) {
    (void)in_sizes; (void)n_in; (void)out_size; (void)ws_size;
    const float* x   = (const float*)d_in[0];
    const float* wq  = (const float*)d_in[1];
    const float* wk  = (const float*)d_in[2];
    const float* wv  = (const float*)d_in[3];
    const float* wo  = (const float*)d_in[4];
    const float* rw  = (const float*)d_in[5];
    const float* fc1 = (const float*)d_in[6];
    const float* fc2 = (const float*)d_in[7];
    float* out = (float*)d_out;
    char* ws = (char*)d_ws;
    const size_t MB = 1024*1024;

    // region map (MB), phase-overlaid:
    //  0-16 : wqkv_h(6) wqkv_l(6) wo_h(2) wo_l(2) [prep->WO]  -> oe(16) [moe2->combine]
    // 16-64 : qk_h(16)@16 qk_l(16)@32 vt_h(8)@48 vt_l(8)@56 [QKV->attn/WO]
    //         -> fc1_t(32)@16, fc2_t(32)@48 [post-WO -> moe]
    // 64-80 : h_hi(8) h_lo(8) [rms1->QKV]  -> ao_h(8) ao_l(8) [attn->WO]
    // 80-88 : h bf16 (rms2 out)  [->moe1]
    // 88-120: h1 bf16 (32)       [moe1->moe2]
    // 120+  : meta
    bf16_t* wqkv_h = (bf16_t*)(ws);
    bf16_t* wqkv_l = (bf16_t*)(ws + 6*MB);
    bf16_t* wo_h   = (bf16_t*)(ws + 12*MB);
    bf16_t* wo_l   = (bf16_t*)(ws + 14*MB);
    bf16_t* qk_h   = (bf16_t*)(ws + 16*MB);
    bf16_t* qk_l   = (bf16_t*)(ws + 32*MB);
    bf16_t* vt_h   = (bf16_t*)(ws + 48*MB);
    bf16_t* vt_l   = (bf16_t*)(ws + 56*MB);
    bf16_t* fc1_t  = (bf16_t*)(ws + 16*MB);
    bf16_t* fc2_t  = (bf16_t*)(ws + 48*MB);
    bf16_t* h_hi   = (bf16_t*)(ws + 64*MB);
    bf16_t* h_lo   = (bf16_t*)(ws + 72*MB);
    bf16_t* ao_h   = (bf16_t*)(ws + 64*MB);
    bf16_t* ao_l   = (bf16_t*)(ws + 72*MB);
    bf16_t* h      = (bf16_t*)(ws + 80*MB);
    bf16_t* h1     = (bf16_t*)(ws + 88*MB);
    bf16_t* oe     = (bf16_t*)(ws);
    char* meta = ws + 120*MB;
    int*   idx    = (int*)(meta);
    int*   pos    = (int*)(meta + 64*1024);
    int*   rowmap = (int*)(meta + 128*1024);
    int*   rowpos = (int*)(meta + 192*1024);
    float* wts    = (float*)(meta + 256*1024);
    int*   counts = (int*)(meta + 320*1024);
    int*   offs   = (int*)(meta + 320*1024 + 256);

    const dim3 blk(256);

    // ---- attention path ----
    transp_split_k<<<dim3(32,32), blk, 0, stream>>>(wq, wqkv_h,               wqkv_l,               1024, 1024);
    transp_split_k<<<dim3(32,32), blk, 0, stream>>>(wk, wqkv_h + 1024*1024,   wqkv_l + 1024*1024,   1024, 1024);
    transp_split_k<<<dim3(32,32), blk, 0, stream>>>(wv, wqkv_h + 2*1024*1024, wqkv_l + 2*1024*1024, 1024, 1024);
    transp_split_k<<<dim3(32,32), blk, 0, stream>>>(wo, wo_h,                 wo_l,                 1024, 1024);
    rmsnorm_split_k<<<NTOK, blk, 0, stream>>>(x, h_hi, h_lo);
    gemm_split<3><<<dim3(QKVS/128, NTOK/128), blk, 0, stream>>>(
        h_hi, h_lo, wqkv_h, wqkv_l, nullptr, nullptr, qk_h, qk_l, vt_h, vt_l, QKVS, 1024);
    attn_mfma<<<dim3(16, 16, 2), blk, 0, stream>>>(qk_h, qk_l, vt_h, vt_l, ao_h, ao_l);
    gemm_split<1><<<dim3(DEMB/128, NTOK/128), blk, 0, stream>>>(
        ao_h, ao_l, wo_h, wo_l, x, out, nullptr, nullptr, nullptr, nullptr, DEMB, 1024);

    // ---- MoE path (fp32 router, bf16 experts) ----
    transp_k<<<dim3(64,32,8), blk, 0, stream>>>(fc1, fc1_t, 1024, 2048);
    transp_k<<<dim3(32,64,8), blk, 0, stream>>>(fc2, fc2_t, 2048, 1024);
    rmsnorm_bf_k<<<NTOK, blk, 0, stream>>>(out, h);
    zero8<<<1, 64, 0, stream>>>(counts);
    router_k<<<NTOK/4, blk, 0, stream>>>(out, rw, idx, wts, pos, counts);
    offsets_k<<<1, 64, 0, stream>>>(counts, offs);
    buildmap_k<<<NTOK/256, blk, 0, stream>>>(idx, pos, offs, rowmap, rowpos);
    gemm_moe<2,1><<<dim3(EDIM/128, 32, NEXP), blk, 0, stream>>>(
        h, fc1_t, h1, rowmap, counts, offs, EDIM, 1024);
    gemm_moe<3,0><<<dim3(DEMB/128, 32, NEXP), blk, 0, stream>>>(
        h1, fc2_t, oe, rowmap, counts, offs, DEMB, EDIM);
    combine_k<<<NTOK, blk, 0, stream>>>(oe, rowpos, wts, out);
}